// Round 2
// baseline (283.579 us; speedup 1.0000x reference)
//
#include <hip/hip_runtime.h>

// N=2048, D=512, A=64, NQ=8, G1=G2=8, A1=128.
// Algebra (no softmax): ctx = q (K^T V)/sqrt(a) => per-group fold:
//   S[g]=(xWk+bk)^T(xWv+bv)/sqrt(a); M[g]=sum_q Wq S Wo_q; o[g]=x M[g]+c[g];
//   tier2 same; Wo2p[g]=Wo2[g]@Wo precomputed => M2p = T2@Wo2p,
//   c2p = r2@Wo2p + (bo2@Wo + bo).
// R11 post-mortem: template<S> names were demangled to one symbol (no
// attribution), and the 2-raw-barrier + sched_barrier(0)-fenced pipeline
// REGRESSED the high-residency mega-stage 47.7->85.5us (lockstep convoy +
// fence overhead per 4-MFMA K-step) while helping low-residency stages.
// R12: (a) distinct plain kernel names ksg0..ksg10 -> per-stage rocprof rows;
//      (b) gemm_block uses the verified MINIMAL 2-phase schedule (T3 recipe):
//          issue next tile's global_load_lds BEFORE compute of current tile,
//          ONE __syncthreads() per K-step (its vmcnt(0) drain lands after the
//          MFMAs, paying max(0, lat-compute) instead of lat). No inline asm,
//          no raw barriers, compiler keeps full scheduling freedom.

typedef __bf16 bf16x8 __attribute__((ext_vector_type(8)));
typedef float  f32x4  __attribute__((ext_vector_type(4)));

struct PD { const float* s; void* d; int R, C, Bc, mode, blocks; };
struct PArgs { PD p[20]; int n; };

struct MA {
    const float *x,*bq1,*bo1,*bq2,*bo2,*bo;
    float* out;
    __bf16 *xb,*Wk1t,*Wv1t,*Wq1b,*Wo1t,*Wk2t,*Wv2t,*Wq2b,*Wo2b,*Wot;
    __bf16 *Ktb,*Vtb,*T1b,*M1t,*o1b,*K2tb,*V2tb,*T2b,*Wo2pT,*M2pt;
    float *STf1,*STf2,*kvb1,*kvb2,*c1,*c2p,*bo2p;
    PArgs pa;
    int prepTot;
};

// ---------------- bf16 MFMA GEMM block, C = alpha*(A.B^T) (+bias) ----------
// A: bf16 [M][K] lda (global_load_lds). B: [N][K] ldb k-major — bf16 via
// global_load_lds, or fp32 (BF32=true) converted during staging.
// bz = b*ksplit+ks; b -> (go=b/divq, gi=b%divq). mode: 0=f32, 1=bf16,
// 2=bf16 transposed (C[n][m], ldc=M), 3=f32 atomicAdd. Exact tile multiples.
// Minimal 2-phase pipeline: LDS [2][ A(BM*64B) | B(BN*64B) ]; per K-step:
//   { issue DMA(t+1 -> buf^1); ds_read+MFMA(t on buf); [BF32: ds_write B t+1];
//     __syncthreads(); }   <- single barrier; drain overlaps compute.
template<int BM, int BN, bool BF32>
__device__ __forceinline__ void gemm_block(void* smv,
    const __bf16* __restrict__ A, const void* __restrict__ Bv,
    const float* __restrict__ bias, void* __restrict__ Cv,
    int K, int lda, int ldb, int ldc, int divq, int ksplit,
    long aOut, long aIn, long bOut, long bIn, long cOut, long cIn,
    long biasOut, long biasIn, int hasBias, int mode, float alpha,
    int bx, int by, int bz)
{
    constexpr int MT = BM / 32, NT = BN / 32;
    constexpr int HALF = (BM + BN) * 64;          // bytes per pipeline buffer
    constexpr int AL = BM / 64;                   // A lds-DMA ops / thread
    constexpr int BL = BF32 ? 0 : BN / 64;        // B lds-DMA ops / thread

    char* smc = (char*)smv;

    int b  = bz / ksplit, ks = bz - b * ksplit;
    int go = b / divq,  gi = b - go * divq;
    A += go * aOut + gi * aIn;
    const __bf16* Bb = (const __bf16*)Bv + (BF32 ? 0 : (go * bOut + gi * bIn));
    const float*  Bf = (const float*)Bv + (BF32 ? (go * bOut + gi * bIn) : 0);
    long cBase = go * cOut + gi * cIn;
    if (hasBias) bias += go * biasOut + gi * biasIn;

    int kChunk = K / ksplit;
    int k0 = ks * kChunk;
    int nT = kChunk / 32;

    int bm = by * BM, bn = bx * BN;
    int tid = threadIdx.x, wave = tid >> 6, lane = tid & 63;
    int wm = (wave >> 1) * (BM / 2), wn = (wave & 1) * (BN / 2);
    int mrow = lane & 15, quad = lane >> 4;

    f32x4 acc[MT][NT];
    #pragma unroll
    for (int i = 0; i < MT; ++i)
        #pragma unroll
        for (int j = 0; j < NT; ++j)
            acc[i][j] = f32x4{0.f, 0.f, 0.f, 0.f};

    // BF32 register staging (issue-early / write-late)
    float4 bf0, bf1;
    int brow = tid >> 2, bcb = (tid & 3) * 8;

    auto loadBf32 = [&](int kk) {
        const float* src = Bf + (long)(bn + brow) * ldb + kk + bcb;
        bf0 = *(const float4*)(src);
        bf1 = *(const float4*)(src + 4);
    };
    auto writeBf32 = [&](int buf) {
        bf16x8 v = {(__bf16)bf0.x, (__bf16)bf0.y, (__bf16)bf0.z, (__bf16)bf0.w,
                    (__bf16)bf1.x, (__bf16)bf1.y, (__bf16)bf1.z, (__bf16)bf1.w};
        *(bf16x8*)(smc + buf * HALF + BM * 64 + brow * 64 + bcb * 2) = v;
    };
    auto issueAB = [&](int buf, int kk) {
        char* base = smc + buf * HALF;
        #pragma unroll
        for (int t = 0; t < AL; ++t) {
            int c = tid + t * 256;
            int row = c >> 2, kq = c & 3;
            __builtin_amdgcn_global_load_lds(
                (const __attribute__((address_space(1))) void*)
                    (A + (long)(bm + row) * lda + kk + kq * 8),
                (__attribute__((address_space(3))) void*)(base + row * 64 + kq * 16),
                16, 0, 0);
        }
        if constexpr (!BF32) {
            #pragma unroll
            for (int t = 0; t < BL; ++t) {
                int c = tid + t * 256;
                int row = c >> 2, kq = c & 3;
                __builtin_amdgcn_global_load_lds(
                    (const __attribute__((address_space(1))) void*)
                        (Bb + (long)(bn + row) * ldb + kk + kq * 8),
                    (__attribute__((address_space(3))) void*)
                        (base + BM * 64 + row * 64 + kq * 16),
                    16, 0, 0);
            }
        }
    };

    // ---- prologue: stage tile 0 into buffer 0, drain once ----
    if constexpr (BF32) loadBf32(k0);
    issueAB(0, k0);
    if constexpr (BF32) writeBf32(0);   // compiler waits bf0/bf1 vmcnt here
    __syncthreads();

    int cur = 0;
    for (int t = 0; t < nT; ++t) {
        int kk = k0 + (t + 1) * 32;
        if (t + 1 < nT) {
            if constexpr (BF32) loadBf32(kk);  // f32 regs for tile t+1
            issueAB(cur ^ 1, kk);              // DMA tile t+1 (in flight across MFMA)
        }

        char* base = smc + cur * HALF;
        bf16x8 af[MT], bfv[NT];
        #pragma unroll
        for (int mt = 0; mt < MT; ++mt)
            af[mt] = *(const bf16x8*)(base + (wm + mt * 16 + mrow) * 64 + quad * 16);
        #pragma unroll
        for (int nt = 0; nt < NT; ++nt)
            bfv[nt] = *(const bf16x8*)(base + BM * 64 + (wn + nt * 16 + mrow) * 64 + quad * 16);
        #pragma unroll
        for (int mt = 0; mt < MT; ++mt)
            #pragma unroll
            for (int nt = 0; nt < NT; ++nt)
                acc[mt][nt] = __builtin_amdgcn_mfma_f32_16x16x32_bf16(
                    af[mt], bfv[nt], acc[mt][nt], 0, 0, 0);

        if constexpr (BF32) {
            if (t + 1 < nT) writeBf32(cur ^ 1);  // convert+store tile t+1 B
        }

        __syncthreads();   // vmcnt(0)+lgkm(0)+barrier: tile t+1 ready, buf cur free
        cur ^= 1;
    }

    #pragma unroll
    for (int mt = 0; mt < MT; ++mt) {
        #pragma unroll
        for (int r = 0; r < 4; ++r) {
            int row = bm + wm + mt * 16 + quad * 4 + r;
            #pragma unroll
            for (int nt = 0; nt < NT; ++nt) {
                int col = bn + wn + nt * 16 + mrow;
                float v = acc[mt][nt][r] * alpha;
                if (hasBias) v += bias[col];
                if (mode == 0)
                    ((float*)Cv)[cBase + (long)row * ldc + col] = v;
                else if (mode == 1)
                    ((__bf16*)Cv)[cBase + (long)row * ldc + col] = (__bf16)v;
                else if (mode == 2)
                    ((__bf16*)Cv)[cBase + (long)col * ldc + row] = (__bf16)v;
                else
                    atomicAdd(&((float*)Cv)[cBase + (long)row * ldc + col], v);
            }
        }
    }
}

// ---------------- prep block: converts/transposes/zeros ---------------------
__device__ __forceinline__ void prep_block(const PArgs& a, int bid, void* smv)
{
    int i = 0;
    while (i < a.n && bid >= a.p[i].blocks) { bid -= a.p[i].blocks; ++i; }
    if (i >= a.n) return;
    PD d = a.p[i];
    int t = threadIdx.x;
    if (d.mode == 0) {
        float (*tile)[33] = (float(*)[33])smv;
        int tC = d.C >> 5, tR = d.R >> 5;
        int batch = bid / (tC * tR), rem = bid - batch * (tC * tR);
        int tyo = rem / tC, txo = rem - tyo * tC;
        const float* src = d.s + (long)batch * d.R * d.C;
        __bf16* dst = (__bf16*)d.d + (long)batch * d.R * d.C;
        int tx = t & 31, ty = t >> 5;
        int r0 = tyo * 32, c0 = txo * 32;
        #pragma unroll
        for (int u = 0; u < 4; ++u)
            tile[ty + 8 * u][tx] = src[(long)(r0 + ty + 8 * u) * d.C + c0 + tx];
        __syncthreads();
        #pragma unroll
        for (int u = 0; u < 4; ++u)
            dst[(long)(c0 + ty + 8 * u) * d.R + r0 + tx] = (__bf16)tile[tx][ty + 8 * u];
    } else if (d.mode == 1) {
        long idx = ((long)bid * 256 + t) * 4;
        long total = (long)d.Bc * d.R * d.C;
        if (idx < total) {
            float4 f = *(const float4*)(d.s + idx);
            __bf16* o = (__bf16*)d.d + idx;
            o[0] = (__bf16)f.x; o[1] = (__bf16)f.y;
            o[2] = (__bf16)f.z; o[3] = (__bf16)f.w;
        }
    } else {
        long idx = (long)bid * 256 + t;
        long total = (long)d.Bc * d.R * d.C;
        if (idx < total) {
            float* o = (float*)d.d;
            if (d.mode == 2) o[idx] = d.s[idx];
            else             o[idx] = 0.f;
        }
    }
}

// ---------------- small block: fused r,c (c-only; S read as fp32) -----------
__device__ __forceinline__ void small_block(void* smv,
    const float* __restrict__ STf, const float* __restrict__ bq,
    const __bf16* __restrict__ WoT, const float* __restrict__ boA,
    float* __restrict__ cOut, int ad, int F, long wG, int bid)
{
    int tid = threadIdx.x;
    float* rL  = (float*)smv;
    float* red = (float*)((char*)smv + 4096);
    int g = bid >> 5, slice = bid & 31;
    int nq = F / ad;
    const float* Sg = STf + (long)g * ad * ad;
    for (int f = tid; f < F; f += 256) {
        int q = f / ad, aa = f - q * ad;
        const float* bv = bq + (long)(g * nq + q) * ad;
        const float* Sa = Sg + (long)aa * ad;
        float s = 0.f;
        for (int c = 0; c < ad; c += 4) {
            float4 b4 = *(const float4*)(bv + c);
            float4 s4 = *(const float4*)(Sa + c);
            s += b4.x * s4.x + b4.y * s4.y + b4.z * s4.z + b4.w * s4.w;
        }
        rL[f] = s;
    }
    __syncthreads();
    int dl = tid & 15, fs = tid >> 4;
    int d = slice * 16 + dl;
    int fchunk = F >> 4;
    const __bf16* wrow = WoT + (long)g * wG + (long)d * F;
    float s = 0.f;
    for (int f0 = fs * fchunk; f0 < (fs + 1) * fchunk; f0 += 8) {
        bf16x8 w = *(const bf16x8*)(wrow + f0);
        s += rL[f0]     * (float)w[0] + rL[f0 + 1] * (float)w[1]
           + rL[f0 + 2] * (float)w[2] + rL[f0 + 3] * (float)w[3]
           + rL[f0 + 4] * (float)w[4] + rL[f0 + 5] * (float)w[5]
           + rL[f0 + 6] * (float)w[6] + rL[f0 + 7] * (float)w[7];
    }
    red[tid] = s;
    __syncthreads();
    if (fs == 0) {
        float tsum = s;
        #pragma unroll
        for (int u = 1; u < 16; ++u) tsum += red[u * 16 + dl];
        cOut[(long)g * 512 + d] = boA[(long)g * 512 + d] + tsum;
    }
}

// outp[g][d] = bias[d] + sum_f v[g][f] * WT[d][f]   (F=512)
__device__ __forceinline__ void vecmat_block(void* smv,
    const float* __restrict__ v, const __bf16* __restrict__ WT,
    const float* __restrict__ bias, float* __restrict__ outp, int g, int slice)
{
    float* red2 = (float*)smv;
    int tid = threadIdx.x;
    int dl = tid & 15, fs = tid >> 4;
    int d = slice * 16 + dl;
    const float* vg = v + (long)g * 512;
    const __bf16* wrow = WT + (long)d * 512;
    float s = 0.f;
    for (int f0 = fs * 32; f0 < (fs + 1) * 32; f0 += 8) {
        bf16x8 w = *(const bf16x8*)(wrow + f0);
        s += vg[f0]     * (float)w[0] + vg[f0 + 1] * (float)w[1]
           + vg[f0 + 2] * (float)w[2] + vg[f0 + 3] * (float)w[3]
           + vg[f0 + 4] * (float)w[4] + vg[f0 + 5] * (float)w[5]
           + vg[f0 + 6] * (float)w[6] + vg[f0 + 7] * (float)w[7];
    }
    red2[tid] = s;
    __syncthreads();
    if (fs == 0) {
        float tsum = s;
        #pragma unroll
        for (int u = 1; u < 16; ++u) tsum += red2[u * 16 + dl];
        outp[(long)g * 512 + d] = bias[d] + tsum;
    }
}

// ---------------- stages 0..10 (compile-time dispatch) ----------------------
template<int S>
__device__ __forceinline__ void run_stage(const MA& a, int vb, void* sm)
{
    const float isa1 = 0.08838834764831845f;  // 1/sqrt(128)
    if constexpr (S == 0) {
        prep_block(a.pa, vb, sm);
    } else if constexpr (S == 1) {   // KV1 (1024) | Wo2p (512) | bo2p (256)
        if (vb < 1024)
            gemm_block<64,64,false>(sm, a.xb, a.Wk1t, a.kvb1, a.Ktb,
                512, 512, 512, 2048, 1, 1,
                0L, 0L, 65536L, 0L, 262144L, 0L, 128L, 0L, 1, 2, 1.0f,
                vb & 1, (vb >> 1) & 31, vb >> 6);
        else if (vb < 1536) {
            int v = vb - 1024;
            gemm_block<64,64,false>(sm, a.Wo2b, a.Wot, nullptr, a.Wo2pT,
                512, 512, 512, 512, 1, 1,
                262144L, 0L, 0L, 0L, 262144L, 0L, 0L, 0L, 0, 2, 1.0f,
                v & 7, (v >> 3) & 7, v >> 6);
        } else {
            int v = vb - 1536;
            vecmat_block(sm, a.bo2, a.Wot, a.bo, a.bo2p, v & 7, v >> 3);
        }
    } else if constexpr (S == 2) {   // S1^T split-K x8 atomic (256)
        gemm_block<64,64,false>(sm, a.Vtb, a.Ktb, nullptr, a.STf1,
            2048, 2048, 2048, 128, 1, 8,
            262144L, 0L, 262144L, 0L, 16384L, 0L, 0L, 0L, 0, 3, isa1,
            vb & 1, (vb >> 1) & 1, vb >> 2);
    } else if constexpr (S == 3) {   // T1 from fp32 S (1024) | c1 (256)
        if (vb < 1024)
            gemm_block<64,64,true>(sm, a.Wq1b, a.STf1, nullptr, a.T1b,
                128, 128, 128, 1024, 8, 1,
                524288L, 65536L, 16384L, 0L, 524288L, 128L, 0L, 0L, 0, 1, 1.0f,
                vb & 1, (vb >> 1) & 7, vb >> 4);
        else
            small_block(sm, a.STf1, a.bq1, a.Wo1t, a.bo1, a.c1,
                        128, 1024, 524288L, vb - 1024);
    } else if constexpr (S == 4) {   // M1^T (512)
        gemm_block<64,64,false>(sm, a.T1b, a.Wo1t, nullptr, a.M1t,
            1024, 1024, 1024, 512, 1, 1,
            524288L, 0L, 524288L, 0L, 262144L, 0L, 0L, 0L, 0, 2, 1.0f,
            vb & 7, (vb >> 3) & 7, vb >> 6);
    } else if constexpr (S == 5) {   // o1 = x.M1 + c1 (512, 128^2)
        gemm_block<128,128,false>(sm, a.xb, a.M1t, a.c1, a.o1b,
            512, 512, 512, 512, 1, 1,
            0L, 0L, 262144L, 0L, 1048576L, 0L, 512L, 0L, 1, 1, 1.0f,
            vb & 3, (vb >> 2) & 15, vb >> 6);
    } else if constexpr (S == 6) {   // KV2 fused (512)
        gemm_block<64,64,false>(sm, a.o1b, a.Wk2t, a.kvb2, a.K2tb,
            512, 512, 512, 2048, 8, 1,
            0L, 1048576L, 262144L, 32768L, 1048576L, 131072L, 512L, 64L,
            1, 2, 1.0f, 0, vb & 31, vb >> 5);
    } else if constexpr (S == 7) {   // S2^T split-K x16 atomic (128)
        gemm_block<64,64,false>(sm, a.V2tb, a.K2tb, nullptr, a.STf2,
            2048, 2048, 2048, 64, 1, 16,
            131072L, 0L, 131072L, 0L, 4096L, 0L, 0L, 0L, 0, 3, 0.125f,
            0, 0, vb);
    } else if constexpr (S == 8) {   // T2 from fp32 S (512) | c2p (256)
        if (vb < 512)
            gemm_block<64,64,true>(sm, a.Wq2b, a.STf2, nullptr, a.T2b,
                64, 64, 64, 512, 8, 1,
                262144L, 32768L, 4096L, 0L, 262144L, 64L, 0L, 0L, 0, 1, 1.0f,
                0, vb & 7, vb >> 3);
        else
            small_block(sm, a.STf2, a.bq2, a.Wo2pT, a.bo2p, a.c2p,
                        64, 512, 262144L, vb - 512);
    } else if constexpr (S == 9) {   // M2p^T = (T2.Wo2p)^T (512)
        gemm_block<64,64,false>(sm, a.T2b, a.Wo2pT, nullptr, a.M2pt,
            512, 512, 512, 512, 1, 1,
            262144L, 0L, 262144L, 0L, 262144L, 0L, 0L, 0L, 0, 2, 1.0f,
            vb & 7, (vb >> 3) & 7, vb >> 6);
    } else {                         // 10: out = o1.M2p + c2p (512, 128^2)
        gemm_block<128,128,false>(sm, a.o1b, a.M2pt, a.c2p, a.out,
            512, 512, 512, 512, 1, 1,
            1048576L, 0L, 262144L, 0L, 1048576L, 0L, 512L, 0L, 1, 0, 1.0f,
            vb & 3, (vb >> 2) & 15, vb >> 6);
    }
}

// Distinct plain names per stage so rocprof rows attribute unambiguously.
#define STAGE_KERNEL(NAME, S, SMEM)                                          \
__global__ __launch_bounds__(256, 4) void NAME(MA a)                         \
{                                                                            \
    __shared__ __align__(16) unsigned char smem[SMEM];                       \
    run_stage<S>(a, blockIdx.x, smem);                                       \
}

STAGE_KERNEL(ksg0_prep,    0, 16384)
STAGE_KERNEL(ksg1_kv1wo2p, 1, 16384)
STAGE_KERNEL(ksg2_s1t,     2, 16384)
STAGE_KERNEL(ksg3_t1c1,    3, 16384)
STAGE_KERNEL(ksg4_m1t,     4, 16384)
STAGE_KERNEL(ksg5_o1,      5, 32768)
STAGE_KERNEL(ksg6_kv2,     6, 16384)
STAGE_KERNEL(ksg7_s2t,     7, 16384)
STAGE_KERNEL(ksg8_t2c2p,   8, 16384)
STAGE_KERNEL(ksg9_m2pt,    9, 16384)
STAGE_KERNEL(ksg10_out,   10, 32768)

extern "C" void kernel_launch(void* const* d_in, const int* in_sizes, int n_in,
                              void* d_out, int out_size, void* d_ws, size_t ws_size,
                              hipStream_t stream)
{
    MA ma;
    ma.x   = (const float*)d_in[0];
    const float* Wq1 = (const float*)d_in[1];  ma.bq1 = (const float*)d_in[2];
    const float* Wk1 = (const float*)d_in[3];  const float* bk1 = (const float*)d_in[4];
    const float* Wv1 = (const float*)d_in[5];  const float* bv1 = (const float*)d_in[6];
    const float* Wo1 = (const float*)d_in[7];  ma.bo1 = (const float*)d_in[8];
    const float* Wq2 = (const float*)d_in[9];  ma.bq2 = (const float*)d_in[10];
    const float* Wk2 = (const float*)d_in[11]; const float* bk2 = (const float*)d_in[12];
    const float* Wv2 = (const float*)d_in[13]; const float* bv2 = (const float*)d_in[14];
    const float* Wo2 = (const float*)d_in[15]; ma.bo2 = (const float*)d_in[16];
    const float* Wo  = (const float*)d_in[17]; ma.bo  = (const float*)d_in[18];
    ma.out = (float*)d_out;
    (void)in_sizes; (void)n_in; (void)out_size; (void)ws_size;

    __bf16* wb = (__bf16*)d_ws;
    long o = 0;
    ma.xb    = wb + o; o += 1048576;
    ma.Wk1t  = wb + o; o += 524288;
    ma.Wv1t  = wb + o; o += 524288;
    ma.Wq1b  = wb + o; o += 4194304;
    ma.Wo1t  = wb + o; o += 4194304;
    ma.Wk2t  = wb + o; o += 262144;
    ma.Wv2t  = wb + o; o += 262144;
    ma.Wq2b  = wb + o; o += 2097152;
    ma.Wo2b  = wb + o; o += 2097152;   // Wo2 bf16 flat [g][512f][512d]
    ma.Wot   = wb + o; o += 262144;    // Wo^T [512e][512d]
    ma.Ktb   = wb + o; o += 2097152;   // K1^T [g][128][2048]
    ma.Vtb   = wb + o; o += 2097152;
    ma.T1b   = wb + o; o += 4194304;
    ma.M1t   = wb + o; o += 2097152;
    ma.o1b   = wb + o; o += 8388608;
    ma.K2tb  = ma.Ktb;                 // alias: K2^T [g][64][2048]
    ma.V2tb  = ma.Ktb + 1048576;       // alias: V2^T
    ma.T2b   = wb + o; o += 2097152;
    ma.Wo2pT = wb + o; o += 2097152;   // (Wo2@Wo)^T [g][512e][512f]
    ma.M2pt  = wb + o; o += 2097152;
    float* wf = (float*)(wb + o);
    long p = 0;
    ma.STf1 = wf + p; p += 131072;
    ma.STf2 = wf + p; p += 32768;
    ma.kvb1 = wf + p; p += 2048;
    ma.kvb2 = wf + p; p += 1024;
    ma.c1   = wf + p; p += 4096;
    ma.c2p  = wf + p; p += 4096;
    ma.bo2p = wf + p; p += 4096;

    int nd = 0, totB = 0;
    auto add = [&](const float* s, void* d, int R, int C, int Bc, int mode) {
        int blocks;
        long total = (long)Bc * R * C;
        if (mode == 0) blocks = Bc * (R >> 5) * (C >> 5);
        else if (mode == 1) blocks = (int)(total / 1024);
        else blocks = (int)((total + 255) / 256);
        ma.pa.p[nd] = PD{s, d, R, C, Bc, mode, blocks};
        ++nd; totB += blocks;
    };
    add(ma.x, ma.xb,   2048, 512, 1, 1);
    add(Wq1,  ma.Wq1b, 512, 128, 64, 1);
    add(Wq2,  ma.Wq2b, 512, 64, 64, 1);
    add(Wo2,  ma.Wo2b, 512, 512, 8, 1);
    add(Wk1,  ma.Wk1t, 512, 128, 8, 0);
    add(Wv1,  ma.Wv1t, 512, 128, 8, 0);
    add(Wo1,  ma.Wo1t, 1024, 512, 8, 0);
    add(Wk2,  ma.Wk2t, 512, 64, 8, 0);
    add(Wv2,  ma.Wv2t, 512, 64, 8, 0);
    add(Wo,   ma.Wot,  512, 512, 1, 0);
    add(bk1,  ma.kvb1,        1, 1024, 1, 2);
    add(bv1,  ma.kvb1 + 1024, 1, 1024, 1, 2);
    add(bk2,  ma.kvb2,        1, 512, 1, 2);
    add(bv2,  ma.kvb2 + 512,  1, 512, 1, 2);
    add(nullptr, ma.STf1, 1, 131072, 1, 4);
    add(nullptr, ma.STf2, 1, 32768, 1, 4);
    ma.pa.n = nd;
    ma.prepTot = totB;

    ksg0_prep   <<<dim3(ma.prepTot), dim3(256), 0, stream>>>(ma);
    ksg1_kv1wo2p<<<dim3(1792), dim3(256), 0, stream>>>(ma);
    ksg2_s1t    <<<dim3(256),  dim3(256), 0, stream>>>(ma);
    ksg3_t1c1   <<<dim3(1280), dim3(256), 0, stream>>>(ma);
    ksg4_m1t    <<<dim3(512),  dim3(256), 0, stream>>>(ma);
    ksg5_o1     <<<dim3(512),  dim3(256), 0, stream>>>(ma);
    ksg6_kv2    <<<dim3(512),  dim3(256), 0, stream>>>(ma);
    ksg7_s2t    <<<dim3(128),  dim3(256), 0, stream>>>(ma);
    ksg8_t2c2p  <<<dim3(768),  dim3(256), 0, stream>>>(ma);
    ksg9_m2pt   <<<dim3(512),  dim3(256), 0, stream>>>(ma);
    ksg10_out   <<<dim3(512),  dim3(256), 0, stream>>>(ma);
}

// Round 3
// 277.703 us; speedup vs baseline: 1.0212x; 1.0212x over previous
//
#include <hip/hip_runtime.h>

// N=2048, D=512, A=64, NQ=8, G1=G2=8, A1=128.
// Algebra (no softmax): ctx = q (K^T V)/sqrt(a) => per-group fold:
//   S[g]=(xWk+bk)^T(xWv+bv)/sqrt(a); M[g]=sum_q Wq S Wo_q; o[g]=x M[g]+c[g];
//   tier2 same; Wo2p[g]=Wo2[g]@Wo precomputed => M2p = T2@Wo2p,
//   c2p = r2@Wo2p + (bo2@Wo + bo).
// R12 post-mortem: dominator = ksg3_t1c1 (46us, ~23MB at 512GB/s = 8% HBM,
// MfmaUtil 0.8%): latency-starved, NOT schedule-bound (R0/R1/R2 all ~46-86us
// regardless of K-loop style; K=128 -> only 4 steps, pipeline never fills).
// R13: stage 3/8 T-GEMMs rebuilt as SINGLE-SHOT K (ss_gemm): whole K extent
//      staged at once (A via global_load_lds x4/thread, B fp32->bf16
//      x16 float4/thread), ONE barrier, then pure ds_read+MFMA. ~20 memory
//      ops in flight per thread vs ~2. LDS bank fix for 256B-stride rows:
//      XOR chunk swizzle (cg = cp ^ (row&7)) applied on the GLOBAL source
//      (LDS dst of global_load_lds is forced linear: base + lane*16) and on
//      the ds_read side -> b128 reads at the structural floor (8 lanes per
//      4-bank group). BN=full-N kills the 2x A re-read. Stages 3/8 split
//      into gemm/small launches for attribution of small_block cost.

typedef __bf16 bf16x8 __attribute__((ext_vector_type(8)));
typedef float  f32x4  __attribute__((ext_vector_type(4)));

struct PD { const float* s; void* d; int R, C, Bc, mode, blocks; };
struct PArgs { PD p[20]; int n; };

struct MA {
    const float *x,*bq1,*bo1,*bq2,*bo2,*bo;
    float* out;
    __bf16 *xb,*Wk1t,*Wv1t,*Wq1b,*Wo1t,*Wk2t,*Wv2t,*Wq2b,*Wo2b,*Wot;
    __bf16 *Ktb,*Vtb,*T1b,*M1t,*o1b,*K2tb,*V2tb,*T2b,*Wo2pT,*M2pt;
    float *STf1,*STf2,*kvb1,*kvb2,*c1,*c2p,*bo2p;
    PArgs pa;
    int prepTot;
};

// ---------------- single-shot-K GEMM (K fits LDS; one barrier) -------------
// C[g][d*cD + q*cQ + col] = sum_k A[g][(q*512+d)][k] * B[g][col][k]
// A bf16 [4096][KK] per g; B fp32 [BN][KK] per g (converted to bf16 in LDS).
// grid: vb = g*64 + rb  (rb indexes 64 row-blocks of BM=64).
template<int BM, int BN, int KK>
__device__ __forceinline__ void ss_gemm(void* smv,
    const __bf16* __restrict__ A, const float* __restrict__ Bf,
    __bf16* __restrict__ C, long aG, long bG, long cG, int cD, int cQ, int vb)
{
    constexpr int MT = BM / 32, NT = BN / 32, KS = KK / 32;
    constexpr int ACH = (KK * 2) / 16;          // 16B chunks per LDS row
    constexpr int ABYTES = BM * KK * 2;
    constexpr int AITER = ABYTES / 16 / 256;    // A DMA ops per thread
    constexpr int ROWB = KK * 2;                // LDS row bytes (A and B)
    constexpr int F4PT = (BN * KK) / 4 / 256;   // B float4 per thread
    constexpr int TPR  = (KK / 4) / F4PT;       // threads per B row

    char* smc = (char*)smv;
    int g = vb >> 6, rb = vb & 63;
    A  += g * aG + (long)rb * BM * KK;
    Bf += g * bG;
    C  += g * cG;

    int tid = threadIdx.x, wave = tid >> 6, lane = tid & 63;
    int mrow = lane & 15, quad = lane >> 4;

    // A: global -> LDS DMA. LDS dst is linear (HW: base + lane*16); the
    // swizzle lives on the global source chunk: LDS[row][cp] = G[row][cp^(r&7)].
    #pragma unroll
    for (int i = 0; i < AITER; ++i) {
        int c = tid + i * 256;
        int row = c / ACH, cp = c % ACH;
        int cg = cp ^ (row & 7);
        __builtin_amdgcn_global_load_lds(
            (const __attribute__((address_space(1))) void*)(A + (long)row * KK + cg * 8),
            (__attribute__((address_space(3))) void*)(smc + c * 16),
            16, 0, 0);
    }
    // B: fp32 global -> regs -> bf16 LDS, write side carries the same XOR.
    {
        int brow = tid / TPR, bseg = tid % TPR;
        const float4* bsrc = (const float4*)(Bf + (long)brow * KK + bseg * (KK / TPR));
        int cbase = (bseg * (KK / TPR)) >> 3;   // first bf16x8-chunk index
        int bx7 = brow & 7;
        char* bls = smc + ABYTES + (long)brow * ROWB;
        #pragma unroll
        for (int j = 0; j < F4PT / 2; ++j) {
            float4 f0 = bsrc[2 * j], f1 = bsrc[2 * j + 1];
            bf16x8 v = {(__bf16)f0.x, (__bf16)f0.y, (__bf16)f0.z, (__bf16)f0.w,
                        (__bf16)f1.x, (__bf16)f1.y, (__bf16)f1.z, (__bf16)f1.w};
            *(bf16x8*)(bls + (((cbase + j) ^ bx7) << 4)) = v;
        }
    }
    __syncthreads();   // single barrier: drains all DMAs + ds_writes

    int wm = (wave >> 1) * (BM / 2), wn = (wave & 1) * (BN / 2);
    f32x4 acc[MT][NT];
    #pragma unroll
    for (int i = 0; i < MT; ++i)
        #pragma unroll
        for (int j = 0; j < NT; ++j)
            acc[i][j] = f32x4{0.f, 0.f, 0.f, 0.f};

    #pragma unroll
    for (int ks = 0; ks < KS; ++ks) {
        bf16x8 af[MT], bv[NT];
        #pragma unroll
        for (int mt = 0; mt < MT; ++mt) {
            int r = wm + mt * 16 + mrow;
            af[mt] = *(const bf16x8*)(smc + (long)r * ROWB
                        + (((ks * 4 + quad) ^ (r & 7)) << 4));
        }
        #pragma unroll
        for (int nt = 0; nt < NT; ++nt) {
            int r = wn + nt * 16 + mrow;
            bv[nt] = *(const bf16x8*)(smc + ABYTES + (long)r * ROWB
                        + (((ks * 4 + quad) ^ (r & 7)) << 4));
        }
        #pragma unroll
        for (int mt = 0; mt < MT; ++mt)
            #pragma unroll
            for (int nt = 0; nt < NT; ++nt)
                acc[mt][nt] = __builtin_amdgcn_mfma_f32_16x16x32_bf16(
                    af[mt], bv[nt], acc[mt][nt], 0, 0, 0);
    }

    #pragma unroll
    for (int mt = 0; mt < MT; ++mt) {
        #pragma unroll
        for (int r4 = 0; r4 < 4; ++r4) {
            int rl = wm + mt * 16 + quad * 4 + r4;
            int ra = rb * BM + rl;
            int q = ra >> 9, d = ra & 511;
            #pragma unroll
            for (int nt = 0; nt < NT; ++nt) {
                int col = wn + nt * 16 + mrow;
                C[(long)d * cD + q * cQ + col] = (__bf16)acc[mt][nt][r4];
            }
        }
    }
}

// ---------------- bf16 MFMA GEMM block, C = alpha*(A.B^T) (+bias) ----------
// (unchanged R12 minimal 2-phase pipeline — used by the K>=512 stages)
template<int BM, int BN, bool BF32>
__device__ __forceinline__ void gemm_block(void* smv,
    const __bf16* __restrict__ A, const void* __restrict__ Bv,
    const float* __restrict__ bias, void* __restrict__ Cv,
    int K, int lda, int ldb, int ldc, int divq, int ksplit,
    long aOut, long aIn, long bOut, long bIn, long cOut, long cIn,
    long biasOut, long biasIn, int hasBias, int mode, float alpha,
    int bx, int by, int bz)
{
    constexpr int MT = BM / 32, NT = BN / 32;
    constexpr int HALF = (BM + BN) * 64;
    constexpr int AL = BM / 64;
    constexpr int BL = BF32 ? 0 : BN / 64;

    char* smc = (char*)smv;

    int b  = bz / ksplit, ks = bz - b * ksplit;
    int go = b / divq,  gi = b - go * divq;
    A += go * aOut + gi * aIn;
    const __bf16* Bb = (const __bf16*)Bv + (BF32 ? 0 : (go * bOut + gi * bIn));
    const float*  Bf = (const float*)Bv + (BF32 ? (go * bOut + gi * bIn) : 0);
    long cBase = go * cOut + gi * cIn;
    if (hasBias) bias += go * biasOut + gi * biasIn;

    int kChunk = K / ksplit;
    int k0 = ks * kChunk;
    int nT = kChunk / 32;

    int bm = by * BM, bn = bx * BN;
    int tid = threadIdx.x, wave = tid >> 6, lane = tid & 63;
    int wm = (wave >> 1) * (BM / 2), wn = (wave & 1) * (BN / 2);
    int mrow = lane & 15, quad = lane >> 4;

    f32x4 acc[MT][NT];
    #pragma unroll
    for (int i = 0; i < MT; ++i)
        #pragma unroll
        for (int j = 0; j < NT; ++j)
            acc[i][j] = f32x4{0.f, 0.f, 0.f, 0.f};

    float4 bf0, bf1;
    int brow = tid >> 2, bcb = (tid & 3) * 8;

    auto loadBf32 = [&](int kk) {
        const float* src = Bf + (long)(bn + brow) * ldb + kk + bcb;
        bf0 = *(const float4*)(src);
        bf1 = *(const float4*)(src + 4);
    };
    auto writeBf32 = [&](int buf) {
        bf16x8 v = {(__bf16)bf0.x, (__bf16)bf0.y, (__bf16)bf0.z, (__bf16)bf0.w,
                    (__bf16)bf1.x, (__bf16)bf1.y, (__bf16)bf1.z, (__bf16)bf1.w};
        *(bf16x8*)(smc + buf * HALF + BM * 64 + brow * 64 + bcb * 2) = v;
    };
    auto issueAB = [&](int buf, int kk) {
        char* base = smc + buf * HALF;
        #pragma unroll
        for (int t = 0; t < AL; ++t) {
            int c = tid + t * 256;
            int row = c >> 2, kq = c & 3;
            __builtin_amdgcn_global_load_lds(
                (const __attribute__((address_space(1))) void*)
                    (A + (long)(bm + row) * lda + kk + kq * 8),
                (__attribute__((address_space(3))) void*)(base + row * 64 + kq * 16),
                16, 0, 0);
        }
        if constexpr (!BF32) {
            #pragma unroll
            for (int t = 0; t < BL; ++t) {
                int c = tid + t * 256;
                int row = c >> 2, kq = c & 3;
                __builtin_amdgcn_global_load_lds(
                    (const __attribute__((address_space(1))) void*)
                        (Bb + (long)(bn + row) * ldb + kk + kq * 8),
                    (__attribute__((address_space(3))) void*)
                        (base + BM * 64 + row * 64 + kq * 16),
                    16, 0, 0);
            }
        }
    };

    if constexpr (BF32) loadBf32(k0);
    issueAB(0, k0);
    if constexpr (BF32) writeBf32(0);
    __syncthreads();

    int cur = 0;
    for (int t = 0; t < nT; ++t) {
        int kk = k0 + (t + 1) * 32;
        if (t + 1 < nT) {
            if constexpr (BF32) loadBf32(kk);
            issueAB(cur ^ 1, kk);
        }

        char* base = smc + cur * HALF;
        bf16x8 af[MT], bfv[NT];
        #pragma unroll
        for (int mt = 0; mt < MT; ++mt)
            af[mt] = *(const bf16x8*)(base + (wm + mt * 16 + mrow) * 64 + quad * 16);
        #pragma unroll
        for (int nt = 0; nt < NT; ++nt)
            bfv[nt] = *(const bf16x8*)(base + BM * 64 + (wn + nt * 16 + mrow) * 64 + quad * 16);
        #pragma unroll
        for (int mt = 0; mt < MT; ++mt)
            #pragma unroll
            for (int nt = 0; nt < NT; ++nt)
                acc[mt][nt] = __builtin_amdgcn_mfma_f32_16x16x32_bf16(
                    af[mt], bfv[nt], acc[mt][nt], 0, 0, 0);

        if constexpr (BF32) {
            if (t + 1 < nT) writeBf32(cur ^ 1);
        }

        __syncthreads();
        cur ^= 1;
    }

    #pragma unroll
    for (int mt = 0; mt < MT; ++mt) {
        #pragma unroll
        for (int r = 0; r < 4; ++r) {
            int row = bm + wm + mt * 16 + quad * 4 + r;
            #pragma unroll
            for (int nt = 0; nt < NT; ++nt) {
                int col = bn + wn + nt * 16 + mrow;
                float v = acc[mt][nt][r] * alpha;
                if (hasBias) v += bias[col];
                if (mode == 0)
                    ((float*)Cv)[cBase + (long)row * ldc + col] = v;
                else if (mode == 1)
                    ((__bf16*)Cv)[cBase + (long)row * ldc + col] = (__bf16)v;
                else if (mode == 2)
                    ((__bf16*)Cv)[cBase + (long)col * ldc + row] = (__bf16)v;
                else
                    atomicAdd(&((float*)Cv)[cBase + (long)row * ldc + col], v);
            }
        }
    }
}

// ---------------- prep block: converts/transposes/zeros ---------------------
__device__ __forceinline__ void prep_block(const PArgs& a, int bid, void* smv)
{
    int i = 0;
    while (i < a.n && bid >= a.p[i].blocks) { bid -= a.p[i].blocks; ++i; }
    if (i >= a.n) return;
    PD d = a.p[i];
    int t = threadIdx.x;
    if (d.mode == 0) {
        float (*tile)[33] = (float(*)[33])smv;
        int tC = d.C >> 5, tR = d.R >> 5;
        int batch = bid / (tC * tR), rem = bid - batch * (tC * tR);
        int tyo = rem / tC, txo = rem - tyo * tC;
        const float* src = d.s + (long)batch * d.R * d.C;
        __bf16* dst = (__bf16*)d.d + (long)batch * d.R * d.C;
        int tx = t & 31, ty = t >> 5;
        int r0 = tyo * 32, c0 = txo * 32;
        #pragma unroll
        for (int u = 0; u < 4; ++u)
            tile[ty + 8 * u][tx] = src[(long)(r0 + ty + 8 * u) * d.C + c0 + tx];
        __syncthreads();
        #pragma unroll
        for (int u = 0; u < 4; ++u)
            dst[(long)(c0 + ty + 8 * u) * d.R + r0 + tx] = (__bf16)tile[tx][ty + 8 * u];
    } else if (d.mode == 1) {
        long idx = ((long)bid * 256 + t) * 4;
        long total = (long)d.Bc * d.R * d.C;
        if (idx < total) {
            float4 f = *(const float4*)(d.s + idx);
            __bf16* o = (__bf16*)d.d + idx;
            o[0] = (__bf16)f.x; o[1] = (__bf16)f.y;
            o[2] = (__bf16)f.z; o[3] = (__bf16)f.w;
        }
    } else {
        long idx = (long)bid * 256 + t;
        long total = (long)d.Bc * d.R * d.C;
        if (idx < total) {
            float* o = (float*)d.d;
            if (d.mode == 2) o[idx] = d.s[idx];
            else             o[idx] = 0.f;
        }
    }
}

// ---------------- small block: fused r,c (c-only; S read as fp32) -----------
__device__ __forceinline__ void small_block(void* smv,
    const float* __restrict__ STf, const float* __restrict__ bq,
    const __bf16* __restrict__ WoT, const float* __restrict__ boA,
    float* __restrict__ cOut, int ad, int F, long wG, int bid)
{
    int tid = threadIdx.x;
    float* rL  = (float*)smv;
    float* red = (float*)((char*)smv + 4096);
    int g = bid >> 5, slice = bid & 31;
    int nq = F / ad;
    const float* Sg = STf + (long)g * ad * ad;
    for (int f = tid; f < F; f += 256) {
        int q = f / ad, aa = f - q * ad;
        const float* bv = bq + (long)(g * nq + q) * ad;
        const float* Sa = Sg + (long)aa * ad;
        float s = 0.f;
        for (int c = 0; c < ad; c += 4) {
            float4 b4 = *(const float4*)(bv + c);
            float4 s4 = *(const float4*)(Sa + c);
            s += b4.x * s4.x + b4.y * s4.y + b4.z * s4.z + b4.w * s4.w;
        }
        rL[f] = s;
    }
    __syncthreads();
    int dl = tid & 15, fs = tid >> 4;
    int d = slice * 16 + dl;
    int fchunk = F >> 4;
    const __bf16* wrow = WoT + (long)g * wG + (long)d * F;
    float s = 0.f;
    for (int f0 = fs * fchunk; f0 < (fs + 1) * fchunk; f0 += 8) {
        bf16x8 w = *(const bf16x8*)(wrow + f0);
        s += rL[f0]     * (float)w[0] + rL[f0 + 1] * (float)w[1]
           + rL[f0 + 2] * (float)w[2] + rL[f0 + 3] * (float)w[3]
           + rL[f0 + 4] * (float)w[4] + rL[f0 + 5] * (float)w[5]
           + rL[f0 + 6] * (float)w[6] + rL[f0 + 7] * (float)w[7];
    }
    red[tid] = s;
    __syncthreads();
    if (fs == 0) {
        float tsum = s;
        #pragma unroll
        for (int u = 1; u < 16; ++u) tsum += red[u * 16 + dl];
        cOut[(long)g * 512 + d] = boA[(long)g * 512 + d] + tsum;
    }
}

// outp[g][d] = bias[d] + sum_f v[g][f] * WT[d][f]   (F=512)
__device__ __forceinline__ void vecmat_block(void* smv,
    const float* __restrict__ v, const __bf16* __restrict__ WT,
    const float* __restrict__ bias, float* __restrict__ outp, int g, int slice)
{
    float* red2 = (float*)smv;
    int tid = threadIdx.x;
    int dl = tid & 15, fs = tid >> 4;
    int d = slice * 16 + dl;
    const float* vg = v + (long)g * 512;
    const __bf16* wrow = WT + (long)d * 512;
    float s = 0.f;
    for (int f0 = fs * 32; f0 < (fs + 1) * 32; f0 += 8) {
        bf16x8 w = *(const bf16x8*)(wrow + f0);
        s += vg[f0]     * (float)w[0] + vg[f0 + 1] * (float)w[1]
           + vg[f0 + 2] * (float)w[2] + vg[f0 + 3] * (float)w[3]
           + vg[f0 + 4] * (float)w[4] + vg[f0 + 5] * (float)w[5]
           + vg[f0 + 6] * (float)w[6] + vg[f0 + 7] * (float)w[7];
    }
    red2[tid] = s;
    __syncthreads();
    if (fs == 0) {
        float tsum = s;
        #pragma unroll
        for (int u = 1; u < 16; ++u) tsum += red2[u * 16 + dl];
        outp[(long)g * 512 + d] = bias[d] + tsum;
    }
}

// ---------------- remaining loop-GEMM stages (compile-time dispatch) --------
template<int S>
__device__ __forceinline__ void run_stage(const MA& a, int vb, void* sm)
{
    const float isa1 = 0.08838834764831845f;  // 1/sqrt(128)
    if constexpr (S == 0) {
        prep_block(a.pa, vb, sm);
    } else if constexpr (S == 1) {   // KV1 (1024) | Wo2p (512) | bo2p (256)
        if (vb < 1024)
            gemm_block<64,64,false>(sm, a.xb, a.Wk1t, a.kvb1, a.Ktb,
                512, 512, 512, 2048, 1, 1,
                0L, 0L, 65536L, 0L, 262144L, 0L, 128L, 0L, 1, 2, 1.0f,
                vb & 1, (vb >> 1) & 31, vb >> 6);
        else if (vb < 1536) {
            int v = vb - 1024;
            gemm_block<64,64,false>(sm, a.Wo2b, a.Wot, nullptr, a.Wo2pT,
                512, 512, 512, 512, 1, 1,
                262144L, 0L, 0L, 0L, 262144L, 0L, 0L, 0L, 0, 2, 1.0f,
                v & 7, (v >> 3) & 7, v >> 6);
        } else {
            int v = vb - 1536;
            vecmat_block(sm, a.bo2, a.Wot, a.bo, a.bo2p, v & 7, v >> 3);
        }
    } else if constexpr (S == 2) {   // S1^T split-K x8 atomic (256)
        gemm_block<64,64,false>(sm, a.Vtb, a.Ktb, nullptr, a.STf1,
            2048, 2048, 2048, 128, 1, 8,
            262144L, 0L, 262144L, 0L, 16384L, 0L, 0L, 0L, 0, 3, isa1,
            vb & 1, (vb >> 1) & 1, vb >> 2);
    } else if constexpr (S == 4) {   // M1^T (512)
        gemm_block<64,64,false>(sm, a.T1b, a.Wo1t, nullptr, a.M1t,
            1024, 1024, 1024, 512, 1, 1,
            524288L, 0L, 524288L, 0L, 262144L, 0L, 0L, 0L, 0, 2, 1.0f,
            vb & 7, (vb >> 3) & 7, vb >> 6);
    } else if constexpr (S == 5) {   // o1 = x.M1 + c1 (512, 128^2)
        gemm_block<128,128,false>(sm, a.xb, a.M1t, a.c1, a.o1b,
            512, 512, 512, 512, 1, 1,
            0L, 0L, 262144L, 0L, 1048576L, 0L, 512L, 0L, 1, 1, 1.0f,
            vb & 3, (vb >> 2) & 15, vb >> 6);
    } else if constexpr (S == 6) {   // KV2 fused (512)
        gemm_block<64,64,false>(sm, a.o1b, a.Wk2t, a.kvb2, a.K2tb,
            512, 512, 512, 2048, 8, 1,
            0L, 1048576L, 262144L, 32768L, 1048576L, 131072L, 512L, 64L,
            1, 2, 1.0f, 0, vb & 31, vb >> 5);
    } else if constexpr (S == 7) {   // S2^T split-K x16 atomic (128)
        gemm_block<64,64,false>(sm, a.V2tb, a.K2tb, nullptr, a.STf2,
            2048, 2048, 2048, 64, 1, 16,
            131072L, 0L, 131072L, 0L, 4096L, 0L, 0L, 0L, 0, 3, 0.125f,
            0, 0, vb);
    } else if constexpr (S == 9) {   // M2p^T = (T2.Wo2p)^T (512)
        gemm_block<64,64,false>(sm, a.T2b, a.Wo2pT, nullptr, a.M2pt,
            512, 512, 512, 512, 1, 1,
            262144L, 0L, 262144L, 0L, 262144L, 0L, 0L, 0L, 0, 2, 1.0f,
            vb & 7, (vb >> 3) & 7, vb >> 6);
    } else {                         // 10: out = o1.M2p + c2p (512, 128^2)
        gemm_block<128,128,false>(sm, a.o1b, a.M2pt, a.c2p, a.out,
            512, 512, 512, 512, 1, 1,
            1048576L, 0L, 262144L, 0L, 1048576L, 0L, 512L, 0L, 1, 0, 1.0f,
            vb & 3, (vb >> 2) & 15, vb >> 6);
    }
}

// Distinct plain names per stage so rocprof rows attribute unambiguously.
#define STAGE_KERNEL(NAME, S, SMEM)                                          \
__global__ __launch_bounds__(256, 4) void NAME(MA a)                         \
{                                                                            \
    __shared__ __align__(16) unsigned char smem[SMEM];                       \
    run_stage<S>(a, blockIdx.x, smem);                                       \
}

STAGE_KERNEL(ksg0_prep,    0, 16384)
STAGE_KERNEL(ksg1_kv1wo2p, 1, 16384)
STAGE_KERNEL(ksg2_s1t,     2, 16384)
STAGE_KERNEL(ksg4_m1t,     4, 16384)
STAGE_KERNEL(ksg5_o1,      5, 32768)
STAGE_KERNEL(ksg6_kv2,     6, 16384)
STAGE_KERNEL(ksg7_s2t,     7, 16384)
STAGE_KERNEL(ksg9_m2pt,    9, 16384)
STAGE_KERNEL(ksg10_out,   10, 32768)

// Single-shot T-GEMMs + split small blocks (stages 3 and 8).
__global__ __launch_bounds__(256, 4) void ksg3a_t1(MA a)
{
    __shared__ __align__(16) unsigned char smem[49152];  // A 16K + B 32K
    ss_gemm<64,128,128>(smem, a.Wq1b, a.STf1, a.T1b,
                        524288L, 16384L, 524288L, 1024, 128, blockIdx.x);
}
__global__ __launch_bounds__(256, 4) void ksg3b_c1(MA a)
{
    __shared__ __align__(16) unsigned char smem[8192];
    small_block(smem, a.STf1, a.bq1, a.Wo1t, a.bo1, a.c1,
                128, 1024, 524288L, blockIdx.x);
}
__global__ __launch_bounds__(256, 4) void ksg8a_t2(MA a)
{
    __shared__ __align__(16) unsigned char smem[16384];  // A 8K + B 8K
    ss_gemm<64,64,64>(smem, a.Wq2b, a.STf2, a.T2b,
                      262144L, 4096L, 262144L, 512, 64, blockIdx.x);
}
__global__ __launch_bounds__(256, 4) void ksg8b_c2p(MA a)
{
    __shared__ __align__(16) unsigned char smem[8192];
    small_block(smem, a.STf2, a.bq2, a.Wo2pT, a.bo2p, a.c2p,
                64, 512, 262144L, blockIdx.x);
}

extern "C" void kernel_launch(void* const* d_in, const int* in_sizes, int n_in,
                              void* d_out, int out_size, void* d_ws, size_t ws_size,
                              hipStream_t stream)
{
    MA ma;
    ma.x   = (const float*)d_in[0];
    const float* Wq1 = (const float*)d_in[1];  ma.bq1 = (const float*)d_in[2];
    const float* Wk1 = (const float*)d_in[3];  const float* bk1 = (const float*)d_in[4];
    const float* Wv1 = (const float*)d_in[5];  const float* bv1 = (const float*)d_in[6];
    const float* Wo1 = (const float*)d_in[7];  ma.bo1 = (const float*)d_in[8];
    const float* Wq2 = (const float*)d_in[9];  ma.bq2 = (const float*)d_in[10];
    const float* Wk2 = (const float*)d_in[11]; const float* bk2 = (const float*)d_in[12];
    const float* Wv2 = (const float*)d_in[13]; const float* bv2 = (const float*)d_in[14];
    const float* Wo2 = (const float*)d_in[15]; ma.bo2 = (const float*)d_in[16];
    const float* Wo  = (const float*)d_in[17]; ma.bo  = (const float*)d_in[18];
    ma.out = (float*)d_out;
    (void)in_sizes; (void)n_in; (void)out_size; (void)ws_size;

    __bf16* wb = (__bf16*)d_ws;
    long o = 0;
    ma.xb    = wb + o; o += 1048576;
    ma.Wk1t  = wb + o; o += 524288;
    ma.Wv1t  = wb + o; o += 524288;
    ma.Wq1b  = wb + o; o += 4194304;
    ma.Wo1t  = wb + o; o += 4194304;
    ma.Wk2t  = wb + o; o += 262144;
    ma.Wv2t  = wb + o; o += 262144;
    ma.Wq2b  = wb + o; o += 2097152;
    ma.Wo2b  = wb + o; o += 2097152;   // Wo2 bf16 flat [g][512f][512d]
    ma.Wot   = wb + o; o += 262144;    // Wo^T [512e][512d]
    ma.Ktb   = wb + o; o += 2097152;   // K1^T [g][128][2048]
    ma.Vtb   = wb + o; o += 2097152;
    ma.T1b   = wb + o; o += 4194304;
    ma.M1t   = wb + o; o += 2097152;
    ma.o1b   = wb + o; o += 8388608;
    ma.K2tb  = ma.Ktb;                 // alias: K2^T [g][64][2048]
    ma.V2tb  = ma.Ktb + 1048576;       // alias: V2^T
    ma.T2b   = wb + o; o += 2097152;
    ma.Wo2pT = wb + o; o += 2097152;   // (Wo2@Wo)^T [g][512e][512f]
    ma.M2pt  = wb + o; o += 2097152;
    float* wf = (float*)(wb + o);
    long p = 0;
    ma.STf1 = wf + p; p += 131072;
    ma.STf2 = wf + p; p += 32768;
    ma.kvb1 = wf + p; p += 2048;
    ma.kvb2 = wf + p; p += 1024;
    ma.c1   = wf + p; p += 4096;
    ma.c2p  = wf + p; p += 4096;
    ma.bo2p = wf + p; p += 4096;

    int nd = 0, totB = 0;
    auto add = [&](const float* s, void* d, int R, int C, int Bc, int mode) {
        int blocks;
        long total = (long)Bc * R * C;
        if (mode == 0) blocks = Bc * (R >> 5) * (C >> 5);
        else if (mode == 1) blocks = (int)(total / 1024);
        else blocks = (int)((total + 255) / 256);
        ma.pa.p[nd] = PD{s, d, R, C, Bc, mode, blocks};
        ++nd; totB += blocks;
    };
    add(ma.x, ma.xb,   2048, 512, 1, 1);
    add(Wq1,  ma.Wq1b, 512, 128, 64, 1);
    add(Wq2,  ma.Wq2b, 512, 64, 64, 1);
    add(Wo2,  ma.Wo2b, 512, 512, 8, 1);
    add(Wk1,  ma.Wk1t, 512, 128, 8, 0);
    add(Wv1,  ma.Wv1t, 512, 128, 8, 0);
    add(Wo1,  ma.Wo1t, 1024, 512, 8, 0);
    add(Wk2,  ma.Wk2t, 512, 64, 8, 0);
    add(Wv2,  ma.Wv2t, 512, 64, 8, 0);
    add(Wo,   ma.Wot,  512, 512, 1, 0);
    add(bk1,  ma.kvb1,        1, 1024, 1, 2);
    add(bv1,  ma.kvb1 + 1024, 1, 1024, 1, 2);
    add(bk2,  ma.kvb2,        1, 512, 1, 2);
    add(bv2,  ma.kvb2 + 512,  1, 512, 1, 2);
    add(nullptr, ma.STf1, 1, 131072, 1, 4);
    add(nullptr, ma.STf2, 1, 32768, 1, 4);
    ma.pa.n = nd;
    ma.prepTot = totB;

    ksg0_prep   <<<dim3(ma.prepTot), dim3(256), 0, stream>>>(ma);
    ksg1_kv1wo2p<<<dim3(1792), dim3(256), 0, stream>>>(ma);
    ksg2_s1t    <<<dim3(256),  dim3(256), 0, stream>>>(ma);
    ksg3a_t1    <<<dim3(512),  dim3(256), 0, stream>>>(ma);
    ksg3b_c1    <<<dim3(256),  dim3(256), 0, stream>>>(ma);
    ksg4_m1t    <<<dim3(512),  dim3(256), 0, stream>>>(ma);
    ksg5_o1     <<<dim3(512),  dim3(256), 0, stream>>>(ma);
    ksg6_kv2    <<<dim3(512),  dim3(256), 0, stream>>>(ma);
    ksg7_s2t    <<<dim3(128),  dim3(256), 0, stream>>>(ma);
    ksg8a_t2    <<<dim3(512),  dim3(256), 0, stream>>>(ma);
    ksg8b_c2p   <<<dim3(256),  dim3(256), 0, stream>>>(ma);
    ksg9_m2pt   <<<dim3(512),  dim3(256), 0, stream>>>(ma);
    ksg10_out   <<<dim3(512),  dim3(256), 0, stream>>>(ma);
}

// Round 4
// 267.836 us; speedup vs baseline: 1.0588x; 1.0368x over previous
//
#include <hip/hip_runtime.h>

// N=2048, D=512, A=64, NQ=8, G1=G2=8, A1=128.
// Algebra (no softmax): ctx = q (K^T V)/sqrt(a) => per-group fold:
//   S[g]=(xWk+bk)^T(xWv+bv)/sqrt(a); M[g]=sum_q Wq S Wo_q; o[g]=x M[g]+c[g];
//   tier2 same; Wo2p[g]=Wo2[g]@Wo precomputed => M2p = T2@Wo2p,
//   c2p = r2@Wo2p + (bo2@Wo + bo).
// R13 post-mortem: all stages now <40us (top-5 = harness 256MiB poison fills
// @41us, not ours). Total moved only -6us: the 3a/3b split EXPOSED
// small_block (1 blk/CU, serial dot chains) that previously hid under
// co-scheduled GEMM blocks; and mode-2 transposed stores are ~16x
// write-amplified (per-lane 2B stores at 4KB stride -> 1 cache line per
// lane).
// R14: (a) MODE-2 fix: swap MFMA operands (mfma(bfv,af,acc)) so the
//      transposed tile is computed natively (D quad/reg dim <- first
//      operand, mrow dim <- second, per verified m89 mapping); store
//      becomes mrow-contiguous like mode 1. MODE is now a template param.
//      Affects stages 1,4,6,9 (~22MB of transposed bf16 writes).
//      (b) re-merge 3a+3b and 8a+8b so small_block latency hides under
//      ss_gemm blocks again; 11 launches total.

typedef __bf16 bf16x8 __attribute__((ext_vector_type(8)));
typedef float  f32x4  __attribute__((ext_vector_type(4)));

struct PD { const float* s; void* d; int R, C, Bc, mode, blocks; };
struct PArgs { PD p[20]; int n; };

struct MA {
    const float *x,*bq1,*bo1,*bq2,*bo2,*bo;
    float* out;
    __bf16 *xb,*Wk1t,*Wv1t,*Wq1b,*Wo1t,*Wk2t,*Wv2t,*Wq2b,*Wo2b,*Wot;
    __bf16 *Ktb,*Vtb,*T1b,*M1t,*o1b,*K2tb,*V2tb,*T2b,*Wo2pT,*M2pt;
    float *STf1,*STf2,*kvb1,*kvb2,*c1,*c2p,*bo2p;
    PArgs pa;
    int prepTot;
};

// ---------------- single-shot-K GEMM (K fits LDS; one barrier) -------------
// C[g][d*cD + q*cQ + col] = sum_k A[g][(q*512+d)][k] * B[g][col][k]
// A bf16 [4096][KK] per g; B fp32 [BN][KK] per g (converted to bf16 in LDS).
// grid: vb = g*64 + rb  (rb indexes 64 row-blocks of BM=64).
template<int BM, int BN, int KK>
__device__ __forceinline__ void ss_gemm(void* smv,
    const __bf16* __restrict__ A, const float* __restrict__ Bf,
    __bf16* __restrict__ C, long aG, long bG, long cG, int cD, int cQ, int vb)
{
    constexpr int MT = BM / 32, NT = BN / 32, KS = KK / 32;
    constexpr int ACH = (KK * 2) / 16;          // 16B chunks per LDS row
    constexpr int ABYTES = BM * KK * 2;
    constexpr int AITER = ABYTES / 16 / 256;    // A DMA ops per thread
    constexpr int ROWB = KK * 2;                // LDS row bytes (A and B)
    constexpr int F4PT = (BN * KK) / 4 / 256;   // B float4 per thread
    constexpr int TPR  = (KK / 4) / F4PT;       // threads per B row

    char* smc = (char*)smv;
    int g = vb >> 6, rb = vb & 63;
    A  += g * aG + (long)rb * BM * KK;
    Bf += g * bG;
    C  += g * cG;

    int tid = threadIdx.x, wave = tid >> 6, lane = tid & 63;
    int mrow = lane & 15, quad = lane >> 4;

    // A: global -> LDS DMA. LDS dst linear (HW: base + lane*16); swizzle on
    // the global source chunk: LDS[row][cp] = G[row][cp^(r&7)].
    #pragma unroll
    for (int i = 0; i < AITER; ++i) {
        int c = tid + i * 256;
        int row = c / ACH, cp = c % ACH;
        int cg = cp ^ (row & 7);
        __builtin_amdgcn_global_load_lds(
            (const __attribute__((address_space(1))) void*)(A + (long)row * KK + cg * 8),
            (__attribute__((address_space(3))) void*)(smc + c * 16),
            16, 0, 0);
    }
    // B: fp32 global -> regs -> bf16 LDS, write side carries the same XOR.
    {
        int brow = tid / TPR, bseg = tid % TPR;
        const float4* bsrc = (const float4*)(Bf + (long)brow * KK + bseg * (KK / TPR));
        int cbase = (bseg * (KK / TPR)) >> 3;   // first bf16x8-chunk index
        int bx7 = brow & 7;
        char* bls = smc + ABYTES + (long)brow * ROWB;
        #pragma unroll
        for (int j = 0; j < F4PT / 2; ++j) {
            float4 f0 = bsrc[2 * j], f1 = bsrc[2 * j + 1];
            bf16x8 v = {(__bf16)f0.x, (__bf16)f0.y, (__bf16)f0.z, (__bf16)f0.w,
                        (__bf16)f1.x, (__bf16)f1.y, (__bf16)f1.z, (__bf16)f1.w};
            *(bf16x8*)(bls + (((cbase + j) ^ bx7) << 4)) = v;
        }
    }
    __syncthreads();   // single barrier: drains all DMAs + ds_writes

    int wm = (wave >> 1) * (BM / 2), wn = (wave & 1) * (BN / 2);
    f32x4 acc[MT][NT];
    #pragma unroll
    for (int i = 0; i < MT; ++i)
        #pragma unroll
        for (int j = 0; j < NT; ++j)
            acc[i][j] = f32x4{0.f, 0.f, 0.f, 0.f};

    #pragma unroll
    for (int ks = 0; ks < KS; ++ks) {
        bf16x8 af[MT], bv[NT];
        #pragma unroll
        for (int mt = 0; mt < MT; ++mt) {
            int r = wm + mt * 16 + mrow;
            af[mt] = *(const bf16x8*)(smc + (long)r * ROWB
                        + (((ks * 4 + quad) ^ (r & 7)) << 4));
        }
        #pragma unroll
        for (int nt = 0; nt < NT; ++nt) {
            int r = wn + nt * 16 + mrow;
            bv[nt] = *(const bf16x8*)(smc + ABYTES + (long)r * ROWB
                        + (((ks * 4 + quad) ^ (r & 7)) << 4));
        }
        #pragma unroll
        for (int mt = 0; mt < MT; ++mt)
            #pragma unroll
            for (int nt = 0; nt < NT; ++nt)
                acc[mt][nt] = __builtin_amdgcn_mfma_f32_16x16x32_bf16(
                    af[mt], bv[nt], acc[mt][nt], 0, 0, 0);
    }

    #pragma unroll
    for (int mt = 0; mt < MT; ++mt) {
        #pragma unroll
        for (int r4 = 0; r4 < 4; ++r4) {
            int rl = wm + mt * 16 + quad * 4 + r4;
            int ra = rb * BM + rl;
            int q = ra >> 9, d = ra & 511;
            #pragma unroll
            for (int nt = 0; nt < NT; ++nt) {
                int col = wn + nt * 16 + mrow;
                C[(long)d * cD + q * cQ + col] = (__bf16)acc[mt][nt][r4];
            }
        }
    }
}

// ---------------- bf16 MFMA GEMM block, C = alpha*(A.B^T) (+bias) ----------
// MODE: 0=f32, 1=bf16, 2=bf16 transposed (C[n][m], ldc=M — computed via
// SWAPPED MFMA operands so the store is mrow-contiguous), 3=f32 atomicAdd.
// Minimal 2-phase pipeline: LDS [2][ A(BM*64B) | B(BN*64B) ]; per K-step:
//   { issue DMA(t+1 -> buf^1); ds_read+MFMA(t on buf); [BF32: ds_write B t+1];
//     __syncthreads(); }
template<int BM, int BN, bool BF32, int MODE>
__device__ __forceinline__ void gemm_block(void* smv,
    const __bf16* __restrict__ A, const void* __restrict__ Bv,
    const float* __restrict__ bias, void* __restrict__ Cv,
    int K, int lda, int ldb, int ldc, int divq, int ksplit,
    long aOut, long aIn, long bOut, long bIn, long cOut, long cIn,
    long biasOut, long biasIn, int hasBias, float alpha,
    int bx, int by, int bz)
{
    constexpr int MT = BM / 32, NT = BN / 32;
    constexpr int HALF = (BM + BN) * 64;
    constexpr int AL = BM / 64;
    constexpr int BL = BF32 ? 0 : BN / 64;

    char* smc = (char*)smv;

    int b  = bz / ksplit, ks = bz - b * ksplit;
    int go = b / divq,  gi = b - go * divq;
    A += go * aOut + gi * aIn;
    const __bf16* Bb = (const __bf16*)Bv + (BF32 ? 0 : (go * bOut + gi * bIn));
    const float*  Bf = (const float*)Bv + (BF32 ? (go * bOut + gi * bIn) : 0);
    long cBase = go * cOut + gi * cIn;
    if (hasBias) bias += go * biasOut + gi * biasIn;

    int kChunk = K / ksplit;
    int k0 = ks * kChunk;
    int nT = kChunk / 32;

    int bm = by * BM, bn = bx * BN;
    int tid = threadIdx.x, wave = tid >> 6, lane = tid & 63;
    int wm = (wave >> 1) * (BM / 2), wn = (wave & 1) * (BN / 2);
    int mrow = lane & 15, quad = lane >> 4;

    f32x4 acc[MT][NT];
    #pragma unroll
    for (int i = 0; i < MT; ++i)
        #pragma unroll
        for (int j = 0; j < NT; ++j)
            acc[i][j] = f32x4{0.f, 0.f, 0.f, 0.f};

    float4 bf0, bf1;
    int brow = tid >> 2, bcb = (tid & 3) * 8;

    auto loadBf32 = [&](int kk) {
        const float* src = Bf + (long)(bn + brow) * ldb + kk + bcb;
        bf0 = *(const float4*)(src);
        bf1 = *(const float4*)(src + 4);
    };
    auto writeBf32 = [&](int buf) {
        bf16x8 v = {(__bf16)bf0.x, (__bf16)bf0.y, (__bf16)bf0.z, (__bf16)bf0.w,
                    (__bf16)bf1.x, (__bf16)bf1.y, (__bf16)bf1.z, (__bf16)bf1.w};
        *(bf16x8*)(smc + buf * HALF + BM * 64 + brow * 64 + bcb * 2) = v;
    };
    auto issueAB = [&](int buf, int kk) {
        char* base = smc + buf * HALF;
        #pragma unroll
        for (int t = 0; t < AL; ++t) {
            int c = tid + t * 256;
            int row = c >> 2, kq = c & 3;
            __builtin_amdgcn_global_load_lds(
                (const __attribute__((address_space(1))) void*)
                    (A + (long)(bm + row) * lda + kk + kq * 8),
                (__attribute__((address_space(3))) void*)(base + row * 64 + kq * 16),
                16, 0, 0);
        }
        if constexpr (!BF32) {
            #pragma unroll
            for (int t = 0; t < BL; ++t) {
                int c = tid + t * 256;
                int row = c >> 2, kq = c & 3;
                __builtin_amdgcn_global_load_lds(
                    (const __attribute__((address_space(1))) void*)
                        (Bb + (long)(bn + row) * ldb + kk + kq * 8),
                    (__attribute__((address_space(3))) void*)
                        (base + BM * 64 + row * 64 + kq * 16),
                    16, 0, 0);
            }
        }
    };

    if constexpr (BF32) loadBf32(k0);
    issueAB(0, k0);
    if constexpr (BF32) writeBf32(0);
    __syncthreads();

    int cur = 0;
    for (int t = 0; t < nT; ++t) {
        int kk = k0 + (t + 1) * 32;
        if (t + 1 < nT) {
            if constexpr (BF32) loadBf32(kk);
            issueAB(cur ^ 1, kk);
        }

        char* base = smc + cur * HALF;
        bf16x8 af[MT], bfv[NT];
        #pragma unroll
        for (int mt = 0; mt < MT; ++mt)
            af[mt] = *(const bf16x8*)(base + (wm + mt * 16 + mrow) * 64 + quad * 16);
        #pragma unroll
        for (int nt = 0; nt < NT; ++nt)
            bfv[nt] = *(const bf16x8*)(base + BM * 64 + (wn + nt * 16 + mrow) * 64 + quad * 16);
        #pragma unroll
        for (int mt = 0; mt < MT; ++mt)
            #pragma unroll
            for (int nt = 0; nt < NT; ++nt) {
                if constexpr (MODE == 2)   // transposed output: swap operands
                    acc[mt][nt] = __builtin_amdgcn_mfma_f32_16x16x32_bf16(
                        bfv[nt], af[mt], acc[mt][nt], 0, 0, 0);
                else
                    acc[mt][nt] = __builtin_amdgcn_mfma_f32_16x16x32_bf16(
                        af[mt], bfv[nt], acc[mt][nt], 0, 0, 0);
            }

        if constexpr (BF32) {
            if (t + 1 < nT) writeBf32(cur ^ 1);
        }

        __syncthreads();
        cur ^= 1;
    }

    if constexpr (MODE == 2) {
        // D[i][j]: i <- B-row (quad/reg), j <- A-row (mrow). Store at
        // C[ci*ldc + mi] is mrow-contiguous (coalesced, no amplification).
        #pragma unroll
        for (int nt = 0; nt < NT; ++nt) {
            #pragma unroll
            for (int r = 0; r < 4; ++r) {
                int ci = bn + wn + nt * 16 + quad * 4 + r;
                #pragma unroll
                for (int mt = 0; mt < MT; ++mt) {
                    int mi = bm + wm + mt * 16 + mrow;
                    float v = acc[mt][nt][r] * alpha;
                    if (hasBias) v += bias[ci];
                    ((__bf16*)Cv)[cBase + (long)ci * ldc + mi] = (__bf16)v;
                }
            }
        }
    } else {
        #pragma unroll
        for (int mt = 0; mt < MT; ++mt) {
            #pragma unroll
            for (int r = 0; r < 4; ++r) {
                int row = bm + wm + mt * 16 + quad * 4 + r;
                #pragma unroll
                for (int nt = 0; nt < NT; ++nt) {
                    int col = bn + wn + nt * 16 + mrow;
                    float v = acc[mt][nt][r] * alpha;
                    if (hasBias) v += bias[col];
                    if constexpr (MODE == 0)
                        ((float*)Cv)[cBase + (long)row * ldc + col] = v;
                    else if constexpr (MODE == 1)
                        ((__bf16*)Cv)[cBase + (long)row * ldc + col] = (__bf16)v;
                    else
                        atomicAdd(&((float*)Cv)[cBase + (long)row * ldc + col], v);
                }
            }
        }
    }
}

// ---------------- prep block: converts/transposes/zeros ---------------------
__device__ __forceinline__ void prep_block(const PArgs& a, int bid, void* smv)
{
    int i = 0;
    while (i < a.n && bid >= a.p[i].blocks) { bid -= a.p[i].blocks; ++i; }
    if (i >= a.n) return;
    PD d = a.p[i];
    int t = threadIdx.x;
    if (d.mode == 0) {
        float (*tile)[33] = (float(*)[33])smv;
        int tC = d.C >> 5, tR = d.R >> 5;
        int batch = bid / (tC * tR), rem = bid - batch * (tC * tR);
        int tyo = rem / tC, txo = rem - tyo * tC;
        const float* src = d.s + (long)batch * d.R * d.C;
        __bf16* dst = (__bf16*)d.d + (long)batch * d.R * d.C;
        int tx = t & 31, ty = t >> 5;
        int r0 = tyo * 32, c0 = txo * 32;
        #pragma unroll
        for (int u = 0; u < 4; ++u)
            tile[ty + 8 * u][tx] = src[(long)(r0 + ty + 8 * u) * d.C + c0 + tx];
        __syncthreads();
        #pragma unroll
        for (int u = 0; u < 4; ++u)
            dst[(long)(c0 + ty + 8 * u) * d.R + r0 + tx] = (__bf16)tile[tx][ty + 8 * u];
    } else if (d.mode == 1) {
        long idx = ((long)bid * 256 + t) * 4;
        long total = (long)d.Bc * d.R * d.C;
        if (idx < total) {
            float4 f = *(const float4*)(d.s + idx);
            __bf16* o = (__bf16*)d.d + idx;
            o[0] = (__bf16)f.x; o[1] = (__bf16)f.y;
            o[2] = (__bf16)f.z; o[3] = (__bf16)f.w;
        }
    } else {
        long idx = (long)bid * 256 + t;
        long total = (long)d.Bc * d.R * d.C;
        if (idx < total) {
            float* o = (float*)d.d;
            if (d.mode == 2) o[idx] = d.s[idx];
            else             o[idx] = 0.f;
        }
    }
}

// ---------------- small block: fused r,c (c-only; S read as fp32) -----------
__device__ __forceinline__ void small_block(void* smv,
    const float* __restrict__ STf, const float* __restrict__ bq,
    const __bf16* __restrict__ WoT, const float* __restrict__ boA,
    float* __restrict__ cOut, int ad, int F, long wG, int bid)
{
    int tid = threadIdx.x;
    float* rL  = (float*)smv;
    float* red = (float*)((char*)smv + 4096);
    int g = bid >> 5, slice = bid & 31;
    int nq = F / ad;
    const float* Sg = STf + (long)g * ad * ad;
    for (int f = tid; f < F; f += 256) {
        int q = f / ad, aa = f - q * ad;
        const float* bv = bq + (long)(g * nq + q) * ad;
        const float* Sa = Sg + (long)aa * ad;
        float s = 0.f;
        for (int c = 0; c < ad; c += 4) {
            float4 b4 = *(const float4*)(bv + c);
            float4 s4 = *(const float4*)(Sa + c);
            s += b4.x * s4.x + b4.y * s4.y + b4.z * s4.z + b4.w * s4.w;
        }
        rL[f] = s;
    }
    __syncthreads();
    int dl = tid & 15, fs = tid >> 4;
    int d = slice * 16 + dl;
    int fchunk = F >> 4;
    const __bf16* wrow = WoT + (long)g * wG + (long)d * F;
    float s = 0.f;
    for (int f0 = fs * fchunk; f0 < (fs + 1) * fchunk; f0 += 8) {
        bf16x8 w = *(const bf16x8*)(wrow + f0);
        s += rL[f0]     * (float)w[0] + rL[f0 + 1] * (float)w[1]
           + rL[f0 + 2] * (float)w[2] + rL[f0 + 3] * (float)w[3]
           + rL[f0 + 4] * (float)w[4] + rL[f0 + 5] * (float)w[5]
           + rL[f0 + 6] * (float)w[6] + rL[f0 + 7] * (float)w[7];
    }
    red[tid] = s;
    __syncthreads();
    if (fs == 0) {
        float tsum = s;
        #pragma unroll
        for (int u = 1; u < 16; ++u) tsum += red[u * 16 + dl];
        cOut[(long)g * 512 + d] = boA[(long)g * 512 + d] + tsum;
    }
}

// outp[g][d] = bias[d] + sum_f v[g][f] * WT[d][f]   (F=512)
__device__ __forceinline__ void vecmat_block(void* smv,
    const float* __restrict__ v, const __bf16* __restrict__ WT,
    const float* __restrict__ bias, float* __restrict__ outp, int g, int slice)
{
    float* red2 = (float*)smv;
    int tid = threadIdx.x;
    int dl = tid & 15, fs = tid >> 4;
    int d = slice * 16 + dl;
    const float* vg = v + (long)g * 512;
    const __bf16* wrow = WT + (long)d * 512;
    float s = 0.f;
    for (int f0 = fs * 32; f0 < (fs + 1) * 32; f0 += 8) {
        bf16x8 w = *(const bf16x8*)(wrow + f0);
        s += vg[f0]     * (float)w[0] + vg[f0 + 1] * (float)w[1]
           + vg[f0 + 2] * (float)w[2] + vg[f0 + 3] * (float)w[3]
           + vg[f0 + 4] * (float)w[4] + vg[f0 + 5] * (float)w[5]
           + vg[f0 + 6] * (float)w[6] + vg[f0 + 7] * (float)w[7];
    }
    red2[tid] = s;
    __syncthreads();
    if (fs == 0) {
        float tsum = s;
        #pragma unroll
        for (int u = 1; u < 16; ++u) tsum += red2[u * 16 + dl];
        outp[(long)g * 512 + d] = bias[d] + tsum;
    }
}

// ---------------- stages (compile-time dispatch) ----------------------------
template<int S>
__device__ __forceinline__ void run_stage(const MA& a, int vb, void* sm)
{
    const float isa1 = 0.08838834764831845f;  // 1/sqrt(128)
    if constexpr (S == 0) {
        prep_block(a.pa, vb, sm);
    } else if constexpr (S == 1) {   // KV1 (1024) | Wo2p (512) | bo2p (256)
        if (vb < 1024)
            gemm_block<64,64,false,2>(sm, a.xb, a.Wk1t, a.kvb1, a.Ktb,
                512, 512, 512, 2048, 1, 1,
                0L, 0L, 65536L, 0L, 262144L, 0L, 128L, 0L, 1, 1.0f,
                vb & 1, (vb >> 1) & 31, vb >> 6);
        else if (vb < 1536) {
            int v = vb - 1024;
            gemm_block<64,64,false,2>(sm, a.Wo2b, a.Wot, nullptr, a.Wo2pT,
                512, 512, 512, 512, 1, 1,
                262144L, 0L, 0L, 0L, 262144L, 0L, 0L, 0L, 0, 1.0f,
                v & 7, (v >> 3) & 7, v >> 6);
        } else {
            int v = vb - 1536;
            vecmat_block(sm, a.bo2, a.Wot, a.bo, a.bo2p, v & 7, v >> 3);
        }
    } else if constexpr (S == 2) {   // S1^T split-K x8 atomic (256)
        gemm_block<64,64,false,3>(sm, a.Vtb, a.Ktb, nullptr, a.STf1,
            2048, 2048, 2048, 128, 1, 8,
            262144L, 0L, 262144L, 0L, 16384L, 0L, 0L, 0L, 0, isa1,
            vb & 1, (vb >> 1) & 1, vb >> 2);
    } else if constexpr (S == 3) {   // T1 ss_gemm (512) | c1 (256)
        if (vb < 512)
            ss_gemm<64,128,128>(sm, a.Wq1b, a.STf1, a.T1b,
                                524288L, 16384L, 524288L, 1024, 128, vb);
        else
            small_block(sm, a.STf1, a.bq1, a.Wo1t, a.bo1, a.c1,
                        128, 1024, 524288L, vb - 512);
    } else if constexpr (S == 4) {   // M1^T (512)
        gemm_block<64,64,false,2>(sm, a.T1b, a.Wo1t, nullptr, a.M1t,
            1024, 1024, 1024, 512, 1, 1,
            524288L, 0L, 524288L, 0L, 262144L, 0L, 0L, 0L, 0, 1.0f,
            vb & 7, (vb >> 3) & 7, vb >> 6);
    } else if constexpr (S == 5) {   // o1 = x.M1 + c1 (512, 128^2)
        gemm_block<128,128,false,1>(sm, a.xb, a.M1t, a.c1, a.o1b,
            512, 512, 512, 512, 1, 1,
            0L, 0L, 262144L, 0L, 1048576L, 0L, 512L, 0L, 1, 1.0f,
            vb & 3, (vb >> 2) & 15, vb >> 6);
    } else if constexpr (S == 6) {   // KV2 fused (512)
        gemm_block<64,64,false,2>(sm, a.o1b, a.Wk2t, a.kvb2, a.K2tb,
            512, 512, 512, 2048, 8, 1,
            0L, 1048576L, 262144L, 32768L, 1048576L, 131072L, 512L, 64L,
            1, 1.0f, 0, vb & 31, vb >> 5);
    } else if constexpr (S == 7) {   // S2^T split-K x16 atomic (128)
        gemm_block<64,64,false,3>(sm, a.V2tb, a.K2tb, nullptr, a.STf2,
            2048, 2048, 2048, 64, 1, 16,
            131072L, 0L, 131072L, 0L, 4096L, 0L, 0L, 0L, 0, 0.125f,
            0, 0, vb);
    } else if constexpr (S == 8) {   // T2 ss_gemm (512) | c2p (256)
        if (vb < 512)
            ss_gemm<64,64,64>(sm, a.Wq2b, a.STf2, a.T2b,
                              262144L, 4096L, 262144L, 512, 64, vb);
        else
            small_block(sm, a.STf2, a.bq2, a.Wo2pT, a.bo2p, a.c2p,
                        64, 512, 262144L, vb - 512);
    } else if constexpr (S == 9) {   // M2p^T = (T2.Wo2p)^T (512)
        gemm_block<64,64,false,2>(sm, a.T2b, a.Wo2pT, nullptr, a.M2pt,
            512, 512, 512, 512, 1, 1,
            262144L, 0L, 262144L, 0L, 262144L, 0L, 0L, 0L, 0, 1.0f,
            vb & 7, (vb >> 3) & 7, vb >> 6);
    } else {                         // 10: out = o1.M2p + c2p (512, 128^2)
        gemm_block<128,128,false,0>(sm, a.o1b, a.M2pt, a.c2p, a.out,
            512, 512, 512, 512, 1, 1,
            1048576L, 0L, 262144L, 0L, 1048576L, 0L, 512L, 0L, 1, 1.0f,
            vb & 3, (vb >> 2) & 15, vb >> 6);
    }
}

// Distinct plain names per stage so rocprof rows attribute unambiguously.
#define STAGE_KERNEL(NAME, S, SMEM)                                          \
__global__ __launch_bounds__(256, 4) void NAME(MA a)                         \
{                                                                            \
    __shared__ __align__(16) unsigned char smem[SMEM];                       \
    run_stage<S>(a, blockIdx.x, smem);                                       \
}

STAGE_KERNEL(ksg0_prep,    0, 16384)
STAGE_KERNEL(ksg1_kv1wo2p, 1, 16384)
STAGE_KERNEL(ksg2_s1t,     2, 16384)
STAGE_KERNEL(ksg3_t1c1,    3, 49152)   // ss_gemm A 16K + B 32K
STAGE_KERNEL(ksg4_m1t,     4, 16384)
STAGE_KERNEL(ksg5_o1,      5, 32768)
STAGE_KERNEL(ksg6_kv2,     6, 16384)
STAGE_KERNEL(ksg7_s2t,     7, 16384)
STAGE_KERNEL(ksg8_t2c2p,   8, 16384)
STAGE_KERNEL(ksg9_m2pt,    9, 16384)
STAGE_KERNEL(ksg10_out,   10, 32768)

extern "C" void kernel_launch(void* const* d_in, const int* in_sizes, int n_in,
                              void* d_out, int out_size, void* d_ws, size_t ws_size,
                              hipStream_t stream)
{
    MA ma;
    ma.x   = (const float*)d_in[0];
    const float* Wq1 = (const float*)d_in[1];  ma.bq1 = (const float*)d_in[2];
    const float* Wk1 = (const float*)d_in[3];  const float* bk1 = (const float*)d_in[4];
    const float* Wv1 = (const float*)d_in[5];  const float* bv1 = (const float*)d_in[6];
    const float* Wo1 = (const float*)d_in[7];  ma.bo1 = (const float*)d_in[8];
    const float* Wq2 = (const float*)d_in[9];  ma.bq2 = (const float*)d_in[10];
    const float* Wk2 = (const float*)d_in[11]; const float* bk2 = (const float*)d_in[12];
    const float* Wv2 = (const float*)d_in[13]; const float* bv2 = (const float*)d_in[14];
    const float* Wo2 = (const float*)d_in[15]; ma.bo2 = (const float*)d_in[16];
    const float* Wo  = (const float*)d_in[17]; ma.bo  = (const float*)d_in[18];
    ma.out = (float*)d_out;
    (void)in_sizes; (void)n_in; (void)out_size; (void)ws_size;

    __bf16* wb = (__bf16*)d_ws;
    long o = 0;
    ma.xb    = wb + o; o += 1048576;
    ma.Wk1t  = wb + o; o += 524288;
    ma.Wv1t  = wb + o; o += 524288;
    ma.Wq1b  = wb + o; o += 4194304;
    ma.Wo1t  = wb + o; o += 4194304;
    ma.Wk2t  = wb + o; o += 262144;
    ma.Wv2t  = wb + o; o += 262144;
    ma.Wq2b  = wb + o; o += 2097152;
    ma.Wo2b  = wb + o; o += 2097152;   // Wo2 bf16 flat [g][512f][512d]
    ma.Wot   = wb + o; o += 262144;    // Wo^T [512e][512d]
    ma.Ktb   = wb + o; o += 2097152;   // K1^T [g][128][2048]
    ma.Vtb   = wb + o; o += 2097152;
    ma.T1b   = wb + o; o += 4194304;
    ma.M1t   = wb + o; o += 2097152;
    ma.o1b   = wb + o; o += 8388608;
    ma.K2tb  = ma.Ktb;                 // alias: K2^T [g][64][2048]
    ma.V2tb  = ma.Ktb + 1048576;       // alias: V2^T
    ma.T2b   = wb + o; o += 2097152;
    ma.Wo2pT = wb + o; o += 2097152;   // (Wo2@Wo)^T [g][512e][512f]
    ma.M2pt  = wb + o; o += 2097152;
    float* wf = (float*)(wb + o);
    long p = 0;
    ma.STf1 = wf + p; p += 131072;
    ma.STf2 = wf + p; p += 32768;
    ma.kvb1 = wf + p; p += 2048;
    ma.kvb2 = wf + p; p += 1024;
    ma.c1   = wf + p; p += 4096;
    ma.c2p  = wf + p; p += 4096;
    ma.bo2p = wf + p; p += 4096;

    int nd = 0, totB = 0;
    auto add = [&](const float* s, void* d, int R, int C, int Bc, int mode) {
        int blocks;
        long total = (long)Bc * R * C;
        if (mode == 0) blocks = Bc * (R >> 5) * (C >> 5);
        else if (mode == 1) blocks = (int)(total / 1024);
        else blocks = (int)((total + 255) / 256);
        ma.pa.p[nd] = PD{s, d, R, C, Bc, mode, blocks};
        ++nd; totB += blocks;
    };
    add(ma.x, ma.xb,   2048, 512, 1, 1);
    add(Wq1,  ma.Wq1b, 512, 128, 64, 1);
    add(Wq2,  ma.Wq2b, 512, 64, 64, 1);
    add(Wo2,  ma.Wo2b, 512, 512, 8, 1);
    add(Wk1,  ma.Wk1t, 512, 128, 8, 0);
    add(Wv1,  ma.Wv1t, 512, 128, 8, 0);
    add(Wo1,  ma.Wo1t, 1024, 512, 8, 0);
    add(Wk2,  ma.Wk2t, 512, 64, 8, 0);
    add(Wv2,  ma.Wv2t, 512, 64, 8, 0);
    add(Wo,   ma.Wot,  512, 512, 1, 0);
    add(bk1,  ma.kvb1,        1, 1024, 1, 2);
    add(bv1,  ma.kvb1 + 1024, 1, 1024, 1, 2);
    add(bk2,  ma.kvb2,        1, 512, 1, 2);
    add(bv2,  ma.kvb2 + 512,  1, 512, 1, 2);
    add(nullptr, ma.STf1, 1, 131072, 1, 4);
    add(nullptr, ma.STf2, 1, 32768, 1, 4);
    ma.pa.n = nd;
    ma.prepTot = totB;

    ksg0_prep   <<<dim3(ma.prepTot), dim3(256), 0, stream>>>(ma);
    ksg1_kv1wo2p<<<dim3(1792), dim3(256), 0, stream>>>(ma);
    ksg2_s1t    <<<dim3(256),  dim3(256), 0, stream>>>(ma);
    ksg3_t1c1   <<<dim3(768),  dim3(256), 0, stream>>>(ma);
    ksg4_m1t    <<<dim3(512),  dim3(256), 0, stream>>>(ma);
    ksg5_o1     <<<dim3(512),  dim3(256), 0, stream>>>(ma);
    ksg6_kv2    <<<dim3(512),  dim3(256), 0, stream>>>(ma);
    ksg7_s2t    <<<dim3(128),  dim3(256), 0, stream>>>(ma);
    ksg8_t2c2p  <<<dim3(768),  dim3(256), 0, stream>>>(ma);
    ksg9_m2pt   <<<dim3(512),  dim3(256), 0, stream>>>(ma);
    ksg10_out   <<<dim3(512),  dim3(256), 0, stream>>>(ma);
}

// Round 5
// 257.294 us; speedup vs baseline: 1.1022x; 1.0410x over previous
//
#include <hip/hip_runtime.h>

// N=2048, D=512, A=64, NQ=8, G1=G2=8, A1=128.
// Algebra (no softmax): ctx = q (K^T V)/sqrt(a) => per-group fold:
//   S[g]=(xWk+bk)^T(xWv+bv)/sqrt(a); M[g]=sum_q Wq S Wo_q; o[g]=x M[g]+c[g];
//   tier2 same; Wo2p[g]=Wo2[g]@Wo precomputed => M2p = T2@Wo2p,
//   c2p = r2@Wo2p + (bo2@Wo + bo).
// R14 post-mortem: -10us only; top-5 now all harness poison-fills (41us).
// Standing signal: SQ_LDS_BANK_CONFLICT=327680 every round — gemm_block's
// [row][64B] LDS layout makes every ds_read_b128 fragment an 8-way bank
// conflict (16 lanes, 16 rows, 64B stride = 16 banks). Also BK=32 puts a
// barrier+vmcnt(0) drain every 4-16 MFMAs (m233: that overhead dominates).
// R15: gemm_block rebuilt: BK=64 (half the barriers, 2x DMA depth/step,
//      128B LDS rows) + the ss_gemm XOR chunk swizzle (R13-verified):
//      linear LDS dst, global source chunk cg = cp^(row&7), same XOR on
//      ds_read -> conflict-free (2 lanes/bank). Dead BF32 path deleted
//      (stages 3/8 are ss_gemm). LDS 32KB (64^2) / 64KB (128^2, =2 blk/CU
//      matching their 512-block grids).

typedef __bf16 bf16x8 __attribute__((ext_vector_type(8)));
typedef float  f32x4  __attribute__((ext_vector_type(4)));

struct PD { const float* s; void* d; int R, C, Bc, mode, blocks; };
struct PArgs { PD p[20]; int n; };

struct MA {
    const float *x,*bq1,*bo1,*bq2,*bo2,*bo;
    float* out;
    __bf16 *xb,*Wk1t,*Wv1t,*Wq1b,*Wo1t,*Wk2t,*Wv2t,*Wq2b,*Wo2b,*Wot;
    __bf16 *Ktb,*Vtb,*T1b,*M1t,*o1b,*K2tb,*V2tb,*T2b,*Wo2pT,*M2pt;
    float *STf1,*STf2,*kvb1,*kvb2,*c1,*c2p,*bo2p;
    PArgs pa;
    int prepTot;
};

// ---------------- single-shot-K GEMM (K fits LDS; one barrier) -------------
// C[g][d*cD + q*cQ + col] = sum_k A[g][(q*512+d)][k] * B[g][col][k]
// A bf16 [4096][KK] per g; B fp32 [BN][KK] per g (converted to bf16 in LDS).
// grid: vb = g*64 + rb  (rb indexes 64 row-blocks of BM=64).
template<int BM, int BN, int KK>
__device__ __forceinline__ void ss_gemm(void* smv,
    const __bf16* __restrict__ A, const float* __restrict__ Bf,
    __bf16* __restrict__ C, long aG, long bG, long cG, int cD, int cQ, int vb)
{
    constexpr int MT = BM / 32, NT = BN / 32, KS = KK / 32;
    constexpr int ACH = (KK * 2) / 16;          // 16B chunks per LDS row
    constexpr int ABYTES = BM * KK * 2;
    constexpr int AITER = ABYTES / 16 / 256;    // A DMA ops per thread
    constexpr int ROWB = KK * 2;                // LDS row bytes (A and B)
    constexpr int F4PT = (BN * KK) / 4 / 256;   // B float4 per thread
    constexpr int TPR  = (KK / 4) / F4PT;       // threads per B row

    char* smc = (char*)smv;
    int g = vb >> 6, rb = vb & 63;
    A  += g * aG + (long)rb * BM * KK;
    Bf += g * bG;
    C  += g * cG;

    int tid = threadIdx.x, wave = tid >> 6, lane = tid & 63;
    int mrow = lane & 15, quad = lane >> 4;

    // A: global -> LDS DMA. LDS dst linear (HW: base + lane*16); swizzle on
    // the global source chunk: LDS[row][cp] = G[row][cp^(r&7)].
    #pragma unroll
    for (int i = 0; i < AITER; ++i) {
        int c = tid + i * 256;
        int row = c / ACH, cp = c % ACH;
        int cg = cp ^ (row & 7);
        __builtin_amdgcn_global_load_lds(
            (const __attribute__((address_space(1))) void*)(A + (long)row * KK + cg * 8),
            (__attribute__((address_space(3))) void*)(smc + c * 16),
            16, 0, 0);
    }
    // B: fp32 global -> regs -> bf16 LDS, write side carries the same XOR.
    {
        int brow = tid / TPR, bseg = tid % TPR;
        const float4* bsrc = (const float4*)(Bf + (long)brow * KK + bseg * (KK / TPR));
        int cbase = (bseg * (KK / TPR)) >> 3;   // first bf16x8-chunk index
        int bx7 = brow & 7;
        char* bls = smc + ABYTES + (long)brow * ROWB;
        #pragma unroll
        for (int j = 0; j < F4PT / 2; ++j) {
            float4 f0 = bsrc[2 * j], f1 = bsrc[2 * j + 1];
            bf16x8 v = {(__bf16)f0.x, (__bf16)f0.y, (__bf16)f0.z, (__bf16)f0.w,
                        (__bf16)f1.x, (__bf16)f1.y, (__bf16)f1.z, (__bf16)f1.w};
            *(bf16x8*)(bls + (((cbase + j) ^ bx7) << 4)) = v;
        }
    }
    __syncthreads();   // single barrier: drains all DMAs + ds_writes

    int wm = (wave >> 1) * (BM / 2), wn = (wave & 1) * (BN / 2);
    f32x4 acc[MT][NT];
    #pragma unroll
    for (int i = 0; i < MT; ++i)
        #pragma unroll
        for (int j = 0; j < NT; ++j)
            acc[i][j] = f32x4{0.f, 0.f, 0.f, 0.f};

    #pragma unroll
    for (int ks = 0; ks < KS; ++ks) {
        bf16x8 af[MT], bv[NT];
        #pragma unroll
        for (int mt = 0; mt < MT; ++mt) {
            int r = wm + mt * 16 + mrow;
            af[mt] = *(const bf16x8*)(smc + (long)r * ROWB
                        + (((ks * 4 + quad) ^ (r & 7)) << 4));
        }
        #pragma unroll
        for (int nt = 0; nt < NT; ++nt) {
            int r = wn + nt * 16 + mrow;
            bv[nt] = *(const bf16x8*)(smc + ABYTES + (long)r * ROWB
                        + (((ks * 4 + quad) ^ (r & 7)) << 4));
        }
        #pragma unroll
        for (int mt = 0; mt < MT; ++mt)
            #pragma unroll
            for (int nt = 0; nt < NT; ++nt)
                acc[mt][nt] = __builtin_amdgcn_mfma_f32_16x16x32_bf16(
                    af[mt], bv[nt], acc[mt][nt], 0, 0, 0);
    }

    #pragma unroll
    for (int mt = 0; mt < MT; ++mt) {
        #pragma unroll
        for (int r4 = 0; r4 < 4; ++r4) {
            int rl = wm + mt * 16 + quad * 4 + r4;
            int ra = rb * BM + rl;
            int q = ra >> 9, d = ra & 511;
            #pragma unroll
            for (int nt = 0; nt < NT; ++nt) {
                int col = wn + nt * 16 + mrow;
                C[(long)d * cD + q * cQ + col] = (__bf16)acc[mt][nt][r4];
            }
        }
    }
}

// ---------------- bf16 MFMA GEMM block, C = alpha*(A.B^T) (+bias) ----------
// MODE: 0=f32, 1=bf16, 2=bf16 transposed (C[n][m], ldc=M — swapped MFMA
// operands so the store is mrow-contiguous), 3=f32 atomicAdd.
// BK=64 2-phase pipeline, LDS [2][ A(BM rows x 128B) | B(BN rows x 128B) ],
// XOR-swizzled (linear LDS dst, global source chunk cg=cp^(row&7), same XOR
// on ds_read) -> conflict-free fragment reads. One __syncthreads per 64-K.
template<int BM, int BN, int MODE>
__device__ __forceinline__ void gemm_block(void* smv,
    const __bf16* __restrict__ A, const __bf16* __restrict__ B,
    const float* __restrict__ bias, void* __restrict__ Cv,
    int K, int lda, int ldb, int ldc, int divq, int ksplit,
    long aOut, long aIn, long bOut, long bIn, long cOut, long cIn,
    long biasOut, long biasIn, int hasBias, float alpha,
    int bx, int by, int bz)
{
    constexpr int MT = BM / 32, NT = BN / 32;
    constexpr int ROWB = 128;                 // LDS row bytes (64 bf16)
    constexpr int HALF = (BM + BN) * ROWB;    // bytes per pipeline buffer
    constexpr int AOPS = BM * 8 / 256;        // A DMA ops / thread / step
    constexpr int BOPS = BN * 8 / 256;

    char* smc = (char*)smv;

    int b  = bz / ksplit, ks = bz - b * ksplit;
    int go = b / divq,  gi = b - go * divq;
    A += go * aOut + gi * aIn;
    B += go * bOut + gi * bIn;
    long cBase = go * cOut + gi * cIn;
    if (hasBias) bias += go * biasOut + gi * biasIn;

    int kChunk = K / ksplit;
    int k0 = ks * kChunk;
    int nT = kChunk / 64;

    int bm = by * BM, bn = bx * BN;
    int tid = threadIdx.x, wave = tid >> 6, lane = tid & 63;
    int wm = (wave >> 1) * (BM / 2), wn = (wave & 1) * (BN / 2);
    int mrow = lane & 15, quad = lane >> 4;

    f32x4 acc[MT][NT];
    #pragma unroll
    for (int i = 0; i < MT; ++i)
        #pragma unroll
        for (int j = 0; j < NT; ++j)
            acc[i][j] = f32x4{0.f, 0.f, 0.f, 0.f};

    auto issueAB = [&](int buf, int kk) {
        char* base = smc + buf * HALF;
        #pragma unroll
        for (int t = 0; t < AOPS; ++t) {
            int c = tid + t * 256;
            int row = c >> 3, cp = c & 7;
            int cg = cp ^ (row & 7);
            __builtin_amdgcn_global_load_lds(
                (const __attribute__((address_space(1))) void*)
                    (A + (long)(bm + row) * lda + kk + cg * 8),
                (__attribute__((address_space(3))) void*)(base + c * 16),
                16, 0, 0);
        }
        char* bbase = base + BM * ROWB;
        #pragma unroll
        for (int t = 0; t < BOPS; ++t) {
            int c = tid + t * 256;
            int row = c >> 3, cp = c & 7;
            int cg = cp ^ (row & 7);
            __builtin_amdgcn_global_load_lds(
                (const __attribute__((address_space(1))) void*)
                    (B + (long)(bn + row) * ldb + kk + cg * 8),
                (__attribute__((address_space(3))) void*)(bbase + c * 16),
                16, 0, 0);
        }
    };

    issueAB(0, k0);
    __syncthreads();

    int cur = 0;
    for (int t = 0; t < nT; ++t) {
        if (t + 1 < nT) issueAB(cur ^ 1, k0 + (t + 1) * 64);  // in flight across MFMA

        char* base = smc + cur * HALF;
        #pragma unroll
        for (int k2 = 0; k2 < 2; ++k2) {
            bf16x8 af[MT], bfv[NT];
            #pragma unroll
            for (int mt = 0; mt < MT; ++mt) {
                int r = wm + mt * 16 + mrow;
                af[mt] = *(const bf16x8*)(base + r * ROWB
                            + (((k2 * 4 + quad) ^ (r & 7)) << 4));
            }
            #pragma unroll
            for (int nt = 0; nt < NT; ++nt) {
                int r = wn + nt * 16 + mrow;
                bfv[nt] = *(const bf16x8*)(base + BM * ROWB + r * ROWB
                            + (((k2 * 4 + quad) ^ (r & 7)) << 4));
            }
            #pragma unroll
            for (int mt = 0; mt < MT; ++mt)
                #pragma unroll
                for (int nt = 0; nt < NT; ++nt) {
                    if constexpr (MODE == 2)   // transposed output: swap operands
                        acc[mt][nt] = __builtin_amdgcn_mfma_f32_16x16x32_bf16(
                            bfv[nt], af[mt], acc[mt][nt], 0, 0, 0);
                    else
                        acc[mt][nt] = __builtin_amdgcn_mfma_f32_16x16x32_bf16(
                            af[mt], bfv[nt], acc[mt][nt], 0, 0, 0);
                }
        }

        __syncthreads();   // drains tile t+1 DMA, releases buf cur
        cur ^= 1;
    }

    if constexpr (MODE == 2) {
        // D[i][j]: i <- B-row (quad/reg), j <- A-row (mrow): store coalesced.
        #pragma unroll
        for (int nt = 0; nt < NT; ++nt) {
            #pragma unroll
            for (int r = 0; r < 4; ++r) {
                int ci = bn + wn + nt * 16 + quad * 4 + r;
                #pragma unroll
                for (int mt = 0; mt < MT; ++mt) {
                    int mi = bm + wm + mt * 16 + mrow;
                    float v = acc[mt][nt][r] * alpha;
                    if (hasBias) v += bias[ci];
                    ((__bf16*)Cv)[cBase + (long)ci * ldc + mi] = (__bf16)v;
                }
            }
        }
    } else {
        #pragma unroll
        for (int mt = 0; mt < MT; ++mt) {
            #pragma unroll
            for (int r = 0; r < 4; ++r) {
                int row = bm + wm + mt * 16 + quad * 4 + r;
                #pragma unroll
                for (int nt = 0; nt < NT; ++nt) {
                    int col = bn + wn + nt * 16 + mrow;
                    float v = acc[mt][nt][r] * alpha;
                    if (hasBias) v += bias[col];
                    if constexpr (MODE == 0)
                        ((float*)Cv)[cBase + (long)row * ldc + col] = v;
                    else if constexpr (MODE == 1)
                        ((__bf16*)Cv)[cBase + (long)row * ldc + col] = (__bf16)v;
                    else
                        atomicAdd(&((float*)Cv)[cBase + (long)row * ldc + col], v);
                }
            }
        }
    }
}

// ---------------- prep block: converts/transposes/zeros ---------------------
__device__ __forceinline__ void prep_block(const PArgs& a, int bid, void* smv)
{
    int i = 0;
    while (i < a.n && bid >= a.p[i].blocks) { bid -= a.p[i].blocks; ++i; }
    if (i >= a.n) return;
    PD d = a.p[i];
    int t = threadIdx.x;
    if (d.mode == 0) {
        float (*tile)[33] = (float(*)[33])smv;
        int tC = d.C >> 5, tR = d.R >> 5;
        int batch = bid / (tC * tR), rem = bid - batch * (tC * tR);
        int tyo = rem / tC, txo = rem - tyo * tC;
        const float* src = d.s + (long)batch * d.R * d.C;
        __bf16* dst = (__bf16*)d.d + (long)batch * d.R * d.C;
        int tx = t & 31, ty = t >> 5;
        int r0 = tyo * 32, c0 = txo * 32;
        #pragma unroll
        for (int u = 0; u < 4; ++u)
            tile[ty + 8 * u][tx] = src[(long)(r0 + ty + 8 * u) * d.C + c0 + tx];
        __syncthreads();
        #pragma unroll
        for (int u = 0; u < 4; ++u)
            dst[(long)(c0 + ty + 8 * u) * d.R + r0 + tx] = (__bf16)tile[tx][ty + 8 * u];
    } else if (d.mode == 1) {
        long idx = ((long)bid * 256 + t) * 4;
        long total = (long)d.Bc * d.R * d.C;
        if (idx < total) {
            float4 f = *(const float4*)(d.s + idx);
            __bf16* o = (__bf16*)d.d + idx;
            o[0] = (__bf16)f.x; o[1] = (__bf16)f.y;
            o[2] = (__bf16)f.z; o[3] = (__bf16)f.w;
        }
    } else {
        long idx = (long)bid * 256 + t;
        long total = (long)d.Bc * d.R * d.C;
        if (idx < total) {
            float* o = (float*)d.d;
            if (d.mode == 2) o[idx] = d.s[idx];
            else             o[idx] = 0.f;
        }
    }
}

// ---------------- small block: fused r,c (c-only; S read as fp32) -----------
__device__ __forceinline__ void small_block(void* smv,
    const float* __restrict__ STf, const float* __restrict__ bq,
    const __bf16* __restrict__ WoT, const float* __restrict__ boA,
    float* __restrict__ cOut, int ad, int F, long wG, int bid)
{
    int tid = threadIdx.x;
    float* rL  = (float*)smv;
    float* red = (float*)((char*)smv + 4096);
    int g = bid >> 5, slice = bid & 31;
    int nq = F / ad;
    const float* Sg = STf + (long)g * ad * ad;
    for (int f = tid; f < F; f += 256) {
        int q = f / ad, aa = f - q * ad;
        const float* bv = bq + (long)(g * nq + q) * ad;
        const float* Sa = Sg + (long)aa * ad;
        float s = 0.f;
        for (int c = 0; c < ad; c += 4) {
            float4 b4 = *(const float4*)(bv + c);
            float4 s4 = *(const float4*)(Sa + c);
            s += b4.x * s4.x + b4.y * s4.y + b4.z * s4.z + b4.w * s4.w;
        }
        rL[f] = s;
    }
    __syncthreads();
    int dl = tid & 15, fs = tid >> 4;
    int d = slice * 16 + dl;
    int fchunk = F >> 4;
    const __bf16* wrow = WoT + (long)g * wG + (long)d * F;
    float s = 0.f;
    for (int f0 = fs * fchunk; f0 < (fs + 1) * fchunk; f0 += 8) {
        bf16x8 w = *(const bf16x8*)(wrow + f0);
        s += rL[f0]     * (float)w[0] + rL[f0 + 1] * (float)w[1]
           + rL[f0 + 2] * (float)w[2] + rL[f0 + 3] * (float)w[3]
           + rL[f0 + 4] * (float)w[4] + rL[f0 + 5] * (float)w[5]
           + rL[f0 + 6] * (float)w[6] + rL[f0 + 7] * (float)w[7];
    }
    red[tid] = s;
    __syncthreads();
    if (fs == 0) {
        float tsum = s;
        #pragma unroll
        for (int u = 1; u < 16; ++u) tsum += red[u * 16 + dl];
        cOut[(long)g * 512 + d] = boA[(long)g * 512 + d] + tsum;
    }
}

// outp[g][d] = bias[d] + sum_f v[g][f] * WT[d][f]   (F=512)
__device__ __forceinline__ void vecmat_block(void* smv,
    const float* __restrict__ v, const __bf16* __restrict__ WT,
    const float* __restrict__ bias, float* __restrict__ outp, int g, int slice)
{
    float* red2 = (float*)smv;
    int tid = threadIdx.x;
    int dl = tid & 15, fs = tid >> 4;
    int d = slice * 16 + dl;
    const float* vg = v + (long)g * 512;
    const __bf16* wrow = WT + (long)d * 512;
    float s = 0.f;
    for (int f0 = fs * 32; f0 < (fs + 1) * 32; f0 += 8) {
        bf16x8 w = *(const bf16x8*)(wrow + f0);
        s += vg[f0]     * (float)w[0] + vg[f0 + 1] * (float)w[1]
           + vg[f0 + 2] * (float)w[2] + vg[f0 + 3] * (float)w[3]
           + vg[f0 + 4] * (float)w[4] + vg[f0 + 5] * (float)w[5]
           + vg[f0 + 6] * (float)w[6] + vg[f0 + 7] * (float)w[7];
    }
    red2[tid] = s;
    __syncthreads();
    if (fs == 0) {
        float tsum = s;
        #pragma unroll
        for (int u = 1; u < 16; ++u) tsum += red2[u * 16 + dl];
        outp[(long)g * 512 + d] = bias[d] + tsum;
    }
}

// ---------------- stages (compile-time dispatch) ----------------------------
template<int S>
__device__ __forceinline__ void run_stage(const MA& a, int vb, void* sm)
{
    const float isa1 = 0.08838834764831845f;  // 1/sqrt(128)
    if constexpr (S == 0) {
        prep_block(a.pa, vb, sm);
    } else if constexpr (S == 1) {   // KV1 (1024) | Wo2p (512) | bo2p (256)
        if (vb < 1024)
            gemm_block<64,64,2>(sm, a.xb, a.Wk1t, a.kvb1, a.Ktb,
                512, 512, 512, 2048, 1, 1,
                0L, 0L, 65536L, 0L, 262144L, 0L, 128L, 0L, 1, 1.0f,
                vb & 1, (vb >> 1) & 31, vb >> 6);
        else if (vb < 1536) {
            int v = vb - 1024;
            gemm_block<64,64,2>(sm, a.Wo2b, a.Wot, nullptr, a.Wo2pT,
                512, 512, 512, 512, 1, 1,
                262144L, 0L, 0L, 0L, 262144L, 0L, 0L, 0L, 0, 1.0f,
                v & 7, (v >> 3) & 7, v >> 6);
        } else {
            int v = vb - 1536;
            vecmat_block(sm, a.bo2, a.Wot, a.bo, a.bo2p, v & 7, v >> 3);
        }
    } else if constexpr (S == 2) {   // S1^T split-K x8 atomic (256)
        gemm_block<64,64,3>(sm, a.Vtb, a.Ktb, nullptr, a.STf1,
            2048, 2048, 2048, 128, 1, 8,
            262144L, 0L, 262144L, 0L, 16384L, 0L, 0L, 0L, 0, isa1,
            vb & 1, (vb >> 1) & 1, vb >> 2);
    } else if constexpr (S == 3) {   // T1 ss_gemm (512) | c1 (256)
        if (vb < 512)
            ss_gemm<64,128,128>(sm, a.Wq1b, a.STf1, a.T1b,
                                524288L, 16384L, 524288L, 1024, 128, vb);
        else
            small_block(sm, a.STf1, a.bq1, a.Wo1t, a.bo1, a.c1,
                        128, 1024, 524288L, vb - 512);
    } else if constexpr (S == 4) {   // M1^T (512)
        gemm_block<64,64,2>(sm, a.T1b, a.Wo1t, nullptr, a.M1t,
            1024, 1024, 1024, 512, 1, 1,
            524288L, 0L, 524288L, 0L, 262144L, 0L, 0L, 0L, 0, 1.0f,
            vb & 7, (vb >> 3) & 7, vb >> 6);
    } else if constexpr (S == 5) {   // o1 = x.M1 + c1 (512, 128^2)
        gemm_block<128,128,1>(sm, a.xb, a.M1t, a.c1, a.o1b,
            512, 512, 512, 512, 1, 1,
            0L, 0L, 262144L, 0L, 1048576L, 0L, 512L, 0L, 1, 1.0f,
            vb & 3, (vb >> 2) & 15, vb >> 6);
    } else if constexpr (S == 6) {   // KV2 fused (512)
        gemm_block<64,64,2>(sm, a.o1b, a.Wk2t, a.kvb2, a.K2tb,
            512, 512, 512, 2048, 8, 1,
            0L, 1048576L, 262144L, 32768L, 1048576L, 131072L, 512L, 64L,
            1, 1.0f, 0, vb & 31, vb >> 5);
    } else if constexpr (S == 7) {   // S2^T split-K x16 atomic (128)
        gemm_block<64,64,3>(sm, a.V2tb, a.K2tb, nullptr, a.STf2,
            2048, 2048, 2048, 64, 1, 16,
            131072L, 0L, 131072L, 0L, 4096L, 0L, 0L, 0L, 0, 0.125f,
            0, 0, vb);
    } else if constexpr (S == 8) {   // T2 ss_gemm (512) | c2p (256)
        if (vb < 512)
            ss_gemm<64,64,64>(sm, a.Wq2b, a.STf2, a.T2b,
                              262144L, 4096L, 262144L, 512, 64, vb);
        else
            small_block(sm, a.STf2, a.bq2, a.Wo2pT, a.bo2p, a.c2p,
                        64, 512, 262144L, vb - 512);
    } else if constexpr (S == 9) {   // M2p^T = (T2.Wo2p)^T (512)
        gemm_block<64,64,2>(sm, a.T2b, a.Wo2pT, nullptr, a.M2pt,
            512, 512, 512, 512, 1, 1,
            262144L, 0L, 262144L, 0L, 262144L, 0L, 0L, 0L, 0, 1.0f,
            vb & 7, (vb >> 3) & 7, vb >> 6);
    } else {                         // 10: out = o1.M2p + c2p (512, 128^2)
        gemm_block<128,128,0>(sm, a.o1b, a.M2pt, a.c2p, a.out,
            512, 512, 512, 512, 1, 1,
            1048576L, 0L, 262144L, 0L, 1048576L, 0L, 512L, 0L, 1, 1.0f,
            vb & 3, (vb >> 2) & 15, vb >> 6);
    }
}

// Distinct plain names per stage so rocprof rows attribute unambiguously.
#define STAGE_KERNEL(NAME, S, SMEM, MINW)                                    \
__global__ __launch_bounds__(256, MINW) void NAME(MA a)                      \
{                                                                            \
    __shared__ __align__(16) unsigned char smem[SMEM];                       \
    run_stage<S>(a, blockIdx.x, smem);                                       \
}

STAGE_KERNEL(ksg0_prep,    0, 16384, 4)
STAGE_KERNEL(ksg1_kv1wo2p, 1, 32768, 4)
STAGE_KERNEL(ksg2_s1t,     2, 32768, 4)
STAGE_KERNEL(ksg3_t1c1,    3, 49152, 4)   // ss_gemm A 16K + B 32K
STAGE_KERNEL(ksg4_m1t,     4, 32768, 4)
STAGE_KERNEL(ksg5_o1,      5, 65536, 2)   // 128^2, BK=64 dbuf
STAGE_KERNEL(ksg6_kv2,     6, 32768, 4)
STAGE_KERNEL(ksg7_s2t,     7, 32768, 4)
STAGE_KERNEL(ksg8_t2c2p,   8, 16384, 4)
STAGE_KERNEL(ksg9_m2pt,    9, 32768, 4)
STAGE_KERNEL(ksg10_out,   10, 65536, 2)

extern "C" void kernel_launch(void* const* d_in, const int* in_sizes, int n_in,
                              void* d_out, int out_size, void* d_ws, size_t ws_size,
                              hipStream_t stream)
{
    MA ma;
    ma.x   = (const float*)d_in[0];
    const float* Wq1 = (const float*)d_in[1];  ma.bq1 = (const float*)d_in[2];
    const float* Wk1 = (const float*)d_in[3];  const float* bk1 = (const float*)d_in[4];
    const float* Wv1 = (const float*)d_in[5];  const float* bv1 = (const float*)d_in[6];
    const float* Wo1 = (const float*)d_in[7];  ma.bo1 = (const float*)d_in[8];
    const float* Wq2 = (const float*)d_in[9];  ma.bq2 = (const float*)d_in[10];
    const float* Wk2 = (const float*)d_in[11]; const float* bk2 = (const float*)d_in[12];
    const float* Wv2 = (const float*)d_in[13]; const float* bv2 = (const float*)d_in[14];
    const float* Wo2 = (const float*)d_in[15]; ma.bo2 = (const float*)d_in[16];
    const float* Wo  = (const float*)d_in[17]; ma.bo  = (const float*)d_in[18];
    ma.out = (float*)d_out;
    (void)in_sizes; (void)n_in; (void)out_size; (void)ws_size;

    __bf16* wb = (__bf16*)d_ws;
    long o = 0;
    ma.xb    = wb + o; o += 1048576;
    ma.Wk1t  = wb + o; o += 524288;
    ma.Wv1t  = wb + o; o += 524288;
    ma.Wq1b  = wb + o; o += 4194304;
    ma.Wo1t  = wb + o; o += 4194304;
    ma.Wk2t  = wb + o; o += 262144;
    ma.Wv2t  = wb + o; o += 262144;
    ma.Wq2b  = wb + o; o += 2097152;
    ma.Wo2b  = wb + o; o += 2097152;   // Wo2 bf16 flat [g][512f][512d]
    ma.Wot   = wb + o; o += 262144;    // Wo^T [512e][512d]
    ma.Ktb   = wb + o; o += 2097152;   // K1^T [g][128][2048]
    ma.Vtb   = wb + o; o += 2097152;
    ma.T1b   = wb + o; o += 4194304;
    ma.M1t   = wb + o; o += 2097152;
    ma.o1b   = wb + o; o += 8388608;
    ma.K2tb  = ma.Ktb;                 // alias: K2^T [g][64][2048]
    ma.V2tb  = ma.Ktb + 1048576;       // alias: V2^T
    ma.T2b   = wb + o; o += 2097152;
    ma.Wo2pT = wb + o; o += 2097152;   // (Wo2@Wo)^T [g][512e][512f]
    ma.M2pt  = wb + o; o += 2097152;
    float* wf = (float*)(wb + o);
    long p = 0;
    ma.STf1 = wf + p; p += 131072;
    ma.STf2 = wf + p; p += 32768;
    ma.kvb1 = wf + p; p += 2048;
    ma.kvb2 = wf + p; p += 1024;
    ma.c1   = wf + p; p += 4096;
    ma.c2p  = wf + p; p += 4096;
    ma.bo2p = wf + p; p += 4096;

    int nd = 0, totB = 0;
    auto add = [&](const float* s, void* d, int R, int C, int Bc, int mode) {
        int blocks;
        long total = (long)Bc * R * C;
        if (mode == 0) blocks = Bc * (R >> 5) * (C >> 5);
        else if (mode == 1) blocks = (int)(total / 1024);
        else blocks = (int)((total + 255) / 256);
        ma.pa.p[nd] = PD{s, d, R, C, Bc, mode, blocks};
        ++nd; totB += blocks;
    };
    add(ma.x, ma.xb,   2048, 512, 1, 1);
    add(Wq1,  ma.Wq1b, 512, 128, 64, 1);
    add(Wq2,  ma.Wq2b, 512, 64, 64, 1);
    add(Wo2,  ma.Wo2b, 512, 512, 8, 1);
    add(Wk1,  ma.Wk1t, 512, 128, 8, 0);
    add(Wv1,  ma.Wv1t, 512, 128, 8, 0);
    add(Wo1,  ma.Wo1t, 1024, 512, 8, 0);
    add(Wk2,  ma.Wk2t, 512, 64, 8, 0);
    add(Wv2,  ma.Wv2t, 512, 64, 8, 0);
    add(Wo,   ma.Wot,  512, 512, 1, 0);
    add(bk1,  ma.kvb1,        1, 1024, 1, 2);
    add(bv1,  ma.kvb1 + 1024, 1, 1024, 1, 2);
    add(bk2,  ma.kvb2,        1, 512, 1, 2);
    add(bv2,  ma.kvb2 + 512,  1, 512, 1, 2);
    add(nullptr, ma.STf1, 1, 131072, 1, 4);
    add(nullptr, ma.STf2, 1, 32768, 1, 4);
    ma.pa.n = nd;
    ma.prepTot = totB;

    ksg0_prep   <<<dim3(ma.prepTot), dim3(256), 0, stream>>>(ma);
    ksg1_kv1wo2p<<<dim3(1792), dim3(256), 0, stream>>>(ma);
    ksg2_s1t    <<<dim3(256),  dim3(256), 0, stream>>>(ma);
    ksg3_t1c1   <<<dim3(768),  dim3(256), 0, stream>>>(ma);
    ksg4_m1t    <<<dim3(512),  dim3(256), 0, stream>>>(ma);
    ksg5_o1     <<<dim3(512),  dim3(256), 0, stream>>>(ma);
    ksg6_kv2    <<<dim3(512),  dim3(256), 0, stream>>>(ma);
    ksg7_s2t    <<<dim3(128),  dim3(256), 0, stream>>>(ma);
    ksg8_t2c2p  <<<dim3(768),  dim3(256), 0, stream>>>(ma);
    ksg9_m2pt   <<<dim3(512),  dim3(256), 0, stream>>>(ma);
    ksg10_out   <<<dim3(512),  dim3(256), 0, stream>>>(ma);
}